// Round 14
// baseline (431.632 us; speedup 1.0000x reference)
//
#include <hip/hip_runtime.h>
#include <math.h>

// Problem constants
#define BB 2
#define QQ 16
#define DD 2048
#define HH 16
#define DHH 128
#define PP 8192
#define FF 5632
#define KK 8208
#define BH 32
#define RR 32      // B*Q rows
#define NPRUNE 820

// Workspace layout (float offsets). ws_size ~512 MiB.
#define OFF_X      0u
#define OFF_QR     65536u
#define OFF_KN     131072u
#define OFF_VN     196608u
#define OFF_ROWM   262144u
#define OFF_ROWZ   262656u
#define OFF_OATTN  263168u
#define OFF_H      328704u
#define OFF_Y      394240u
#define OFF_ACT    459776u
#define OFF_UNION  640064u
#define OFF_F64    (OFF_UNION + 2228224u)
#define D_X64      0u
#define D_K64      65536u
#define D_Q64      131072u
#define D_M64      135168u
#define D_Z64      135200u
#define D_SC       135232u
#define D_KEYS     397888u
#define OFF_RANK   (OFF_F64 + 812192u)

// ---------------------------------------------------------------- rmsnorm (f32 main path)
__global__ __launch_bounds__(256) void rmsnorm_kernel(
    const float* __restrict__ in, const float* __restrict__ w,
    float* __restrict__ out)
{
    int r = blockIdx.x;
    const float* x = in + (size_t)r * DD;
    float ss = 0.f;
    for (int c = threadIdx.x; c < DD; c += 256) { float v = x[c]; ss = fmaf(v, v, ss); }
    __shared__ float red[256];
    red[threadIdx.x] = ss;
    __syncthreads();
    for (int off = 128; off > 0; off >>= 1) {
        if (threadIdx.x < off) red[threadIdx.x] += red[threadIdx.x + off];
        __syncthreads();
    }
    float mean = red[0] / (float)DD;
    float scale = 1.0f / sqrtf(mean + 1e-5f);
    for (int c = threadIdx.x; c < DD; c += 256)
        out[(size_t)r * DD + c] = x[c] * scale * w[c];
}

// ---------------------------------------------------------------- mixed-precision rmsnorm for importance path
__global__ __launch_bounds__(64) void rms32mix_kernel(
    const float* __restrict__ in, const float* __restrict__ w,
    double* __restrict__ out)
{
    int r = blockIdx.x;
    const float* x = in + (size_t)r * DD;
    __shared__ float bs[16];
    __shared__ float sscale;
    int tid = threadIdx.x;
    if (tid < 16) {
        const float* a = x + tid * 128;
        float rr[8];
#pragma unroll
        for (int j = 0; j < 8; ++j) { float v = a[j]; rr[j] = __fmul_rn(v, v); }
        for (int i = 8; i < 128; i += 8) {
#pragma unroll
            for (int j = 0; j < 8; ++j) {
                float v = a[i + j];
                rr[j] = __fadd_rn(rr[j], __fmul_rn(v, v));
            }
        }
        float t01 = __fadd_rn(rr[0], rr[1]);
        float t23 = __fadd_rn(rr[2], rr[3]);
        float t45 = __fadd_rn(rr[4], rr[5]);
        float t67 = __fadd_rn(rr[6], rr[7]);
        bs[tid] = __fadd_rn(__fadd_rn(t01, t23), __fadd_rn(t45, t67));
    }
    __syncthreads();
    if (tid == 0) {
        float c[8], d[4], e[2];
#pragma unroll
        for (int i = 0; i < 8; ++i) c[i] = __fadd_rn(bs[2 * i], bs[2 * i + 1]);
#pragma unroll
        for (int i = 0; i < 4; ++i) d[i] = __fadd_rn(c[2 * i], c[2 * i + 1]);
        e[0] = __fadd_rn(d[0], d[1]);
        e[1] = __fadd_rn(d[2], d[3]);
        float s = __fadd_rn(e[0], e[1]);
        float v = __fdiv_rn(s, 2048.0f);
        float ve = __fadd_rn(v, 1e-5f);
        float sq = __fsqrt_rn(ve);
        sscale = __fdiv_rn(1.0f, sq);
    }
    __syncthreads();
    double scd = (double)sscale;
    for (int c = tid; c < DD; c += 64)
        out[(size_t)r * DD + c] = ((double)x[c] * scd) * (double)w[c];
}

// ---------------------------------------------------------------- f64 K/Q projection, pipelined W loads
__global__ __launch_bounds__(256) void proj64_part_kernel(
    const double* __restrict__ x64, const float* __restrict__ wk,
    const float* __restrict__ wq, double* __restrict__ part)
{
    int cc = blockIdx.x, kc = blockIdx.y;
    int tid = threadIdx.x;
    int col = cc * 256 + tid;
    int d0 = kc * 128;
    __shared__ double xs[34 * 128];
    for (int i = tid; i < 34 * 128; i += 256) {
        int r = i >> 7, d = i & 127;
        int srcrow = (r < 32) ? r : ((r == 32) ? 15 : 31);
        xs[i] = x64[(size_t)srcrow * DD + d0 + d];
    }
    __syncthreads();
    double acc[34];
#pragma unroll
    for (int r = 0; r < 34; ++r) acc[r] = 0.0;
    const float* wkp = wk + (size_t)d0 * DD + col;
    const float* wqp = wq + (size_t)d0 * DD + col;

#define P64_LOAD(KB, QB, DOFF)                                    \
    _Pragma("unroll")                                             \
    for (int u = 0; u < 4; ++u) {                                 \
        KB[u] = (double)wkp[(size_t)((DOFF) + u) * DD];           \
        QB[u] = (double)wqp[(size_t)((DOFF) + u) * DD];           \
    }
#define P64_FMA(KB, QB, DOFF)                                     \
    _Pragma("unroll")                                             \
    for (int u = 0; u < 4; ++u) {                                 \
        _Pragma("unroll")                                         \
        for (int r = 0; r < 32; ++r)                              \
            acc[r] = fma(xs[r * 128 + (DOFF) + u], KB[u], acc[r]);\
        acc[32] = fma(xs[32 * 128 + (DOFF) + u], QB[u], acc[32]); \
        acc[33] = fma(xs[33 * 128 + (DOFF) + u], QB[u], acc[33]); \
    }

    double kA[4], qA[4], kB[4], qB[4];
    P64_LOAD(kA, qA, 0);
    for (int d = 0; d < 128; d += 8) {
        P64_LOAD(kB, qB, d + 4);
        P64_FMA(kA, qA, d);
        if (d + 8 < 128) { P64_LOAD(kA, qA, d + 8); }
        P64_FMA(kB, qB, d + 4);
    }
#pragma unroll
    for (int r = 0; r < 34; ++r)
        part[((size_t)kc * 34 + r) * DD + col] = acc[r];
}

// ---------------------------------------------------------------- f64 projection reduce -> k64, q64
__global__ __launch_bounds__(256) void proj64_reduce_kernel(
    const double* __restrict__ part, double* __restrict__ k64,
    double* __restrict__ q64)
{
    int e = blockIdx.x * 256 + threadIdx.x;
    if (e >= 34 * DD) return;
    int r = e >> 11, col = e & 2047;
    double s = 0.0;
    for (int kc = 0; kc < 16; ++kc) s += part[((size_t)kc * 34 + r) * DD + col];
    if (r < 32) k64[(size_t)r * DD + col] = s;
    else        q64[(size_t)(r - 32) * DD + col] = s;
}

// ---------------------------------------------------------------- RoPE with f32-replicated tables, f64 rotation
__global__ __launch_bounds__(256) void rope64_kernel(
    double* __restrict__ k64, double* __restrict__ q64)
{
    int r = blockIdx.x;
    double* row;
    int pos;
    if (r < 32) { row = k64 + (size_t)r * DD; pos = PP + (r & 15); }
    else        { row = q64 + (size_t)(r - 32) * DD; pos = PP + 15; }
#pragma unroll 4
    for (int i = 0; i < 4; ++i) {
        int p = threadIdx.x + 256 * i;
        int h = p >> 6, j = p & 63;
        float pf = (float)pow(10000.0, (double)j / 64.0);
        float invf = __fdiv_rn(1.0f, pf);
        float ang = __fmul_rn((float)pos, invf);
        float cs = (float)cos((double)ang);
        float sn = (float)sin((double)ang);
        int c1 = h * DHH + j, c2 = c1 + 64;
        double v1 = row[c1], v2 = row[c2];
        row[c1] = v1 * (double)cs - v2 * (double)sn;
        row[c2] = v2 * (double)cs + v1 * (double)sn;
    }
}

// ---------------------------------------------------------------- 32-row GEMM, 2 cols/thread, pipelined W loads
template<int DCHUNK>
__global__ __launch_bounds__(256) void gemm32c2(
    const float* __restrict__ A, const float* __restrict__ w0,
    const float* __restrict__ w1, const float* __restrict__ w2,
    float* __restrict__ part, int Kdim, int N, size_t zstride)
{
    int cc = blockIdx.x, kc = blockIdx.y, z = blockIdx.z;
    int tid = threadIdx.x;
    int col0 = cc * 512 + tid;
    int d0 = kc * DCHUNK;
    const float* W = (z == 0) ? w0 : (z == 1) ? w1 : w2;
    __shared__ __align__(16) float xs[32 * DCHUNK];
    for (int i = tid; i < 32 * DCHUNK; i += 256) {
        int r = i / DCHUNK, d = i - r * DCHUNK;
        xs[i] = A[(size_t)r * Kdim + d0 + d];
    }
    __syncthreads();
    float acc0[32], acc1[32];
#pragma unroll
    for (int r = 0; r < 32; ++r) { acc0[r] = 0.f; acc1[r] = 0.f; }
    const float* wp = W + (size_t)d0 * N + col0;

#define G_LOAD(B0, B1, DOFF)                                 \
    _Pragma("unroll")                                        \
    for (int u = 0; u < 8; ++u) {                            \
        B0[u] = wp[(size_t)((DOFF) + u) * N];                \
        B1[u] = wp[(size_t)((DOFF) + u) * N + 256];          \
    }
#define G_FMA(B0, B1, DOFF)                                             \
    _Pragma("unroll")                                                   \
    for (int r = 0; r < 32; ++r) {                                      \
        const float4 x0 = *(const float4*)(xs + r * DCHUNK + (DOFF));   \
        const float4 x1 = *(const float4*)(xs + r * DCHUNK + (DOFF)+4); \
        float a = acc0[r], b = acc1[r];                                 \
        a = fmaf(x0.x, B0[0], a);  b = fmaf(x0.x, B1[0], b);            \
        a = fmaf(x0.y, B0[1], a);  b = fmaf(x0.y, B1[1], b);            \
        a = fmaf(x0.z, B0[2], a);  b = fmaf(x0.z, B1[2], b);            \
        a = fmaf(x0.w, B0[3], a);  b = fmaf(x0.w, B1[3], b);            \
        a = fmaf(x1.x, B0[4], a);  b = fmaf(x1.x, B1[4], b);            \
        a = fmaf(x1.y, B0[5], a);  b = fmaf(x1.y, B1[5], b);            \
        a = fmaf(x1.z, B0[6], a);  b = fmaf(x1.z, B1[6], b);            \
        a = fmaf(x1.w, B0[7], a);  b = fmaf(x1.w, B1[7], b);            \
        acc0[r] = a; acc1[r] = b;                                       \
    }

    float wA0[8], wA1[8], wB0[8], wB1[8];
    G_LOAD(wA0, wA1, 0);
    for (int d = 0; d < DCHUNK; d += 16) {
        G_LOAD(wB0, wB1, d + 8);
        G_FMA(wA0, wA1, d);
        if (d + 16 < DCHUNK) { G_LOAD(wA0, wA1, d + 16); }
        G_FMA(wB0, wB1, d + 8);
    }
    float* dst = part + (size_t)z * zstride;
#pragma unroll
    for (int r = 0; r < 32; ++r) {
        dst[((size_t)(kc * 32 + r)) * N + col0] = acc0[r];
        dst[((size_t)(kc * 32 + r)) * N + col0 + 256] = acc1[r];
    }
}

// ---------------------------------------------------------------- QKV reduce + RoPE, column-parallel
__global__ __launch_bounds__(256) void reduce_qkv_rope(
    const float* __restrict__ part, float* __restrict__ qr,
    float* __restrict__ kn, float* __restrict__ vn)
{
    int r = blockIdx.x;
    int b = r >> 4, qi = r & 15;
    int tid = threadIdx.x;
    int c = blockIdx.y * 256 + tid;
    int h = c >> 7, dh = c & 127, j = dh & 63;

    float invf = (float)exp(-((double)j / 64.0) * log(10000.0));
    float ang = (float)(PP + qi) * invf;
    float sn, cs;
    sincosf(ang, &sn, &cs);

    __shared__ float buf[256];
    size_t dsti = (((size_t)(b * HH + h)) * QQ + qi) * DHH + dh;
    for (int mat = 0; mat < 3; ++mat) {
        const float* pm = part + (size_t)mat * 32 * 65536 + (size_t)r * DD + c;
        float s = 0.f;
#pragma unroll 8
        for (int kc = 0; kc < 32; ++kc)
            s += pm[(size_t)kc * 32 * DD];
        buf[tid] = s;
        __syncthreads();
        float val;
        if (mat == 2) {
            val = s;
        } else {
            float other = (dh < 64) ? -buf[tid + 64] : buf[tid - 64];
            val = s * cs + other * sn;
        }
        float* dst = (mat == 0) ? qr : (mat == 1) ? kn : vn;
        dst[dsti] = val;
        __syncthreads();
    }
}

// ---------------------------------------------------------------- scores: pipelined K loads, f64 split chains
__global__ __launch_bounds__(256) void scores_kernel(
    const float* __restrict__ qr, const float* __restrict__ past_k,
    const float* __restrict__ kn, float* __restrict__ attn,
    const double* __restrict__ q64, const double* __restrict__ k64,
    double* __restrict__ sc64)
{
    int bh = blockIdx.x, ch = blockIdx.y;
    int b = bh >> 4, h = bh & 15;
    int tid = threadIdx.x;
    __shared__ __align__(16) float qs[QQ * DHH];
    __shared__ double q64s[DHH];
    for (int i = tid; i < QQ * DHH; i += 256) qs[i] = qr[(size_t)bh * (QQ * DHH) + i];
    if (tid < DHH) q64s[tid] = q64[(size_t)b * DD + h * DHH + tid];
    __syncthreads();

    if (ch < 16) {
        int kbase = ch * 512;
        const float* kr0 = past_k + ((size_t)bh * PP + kbase + tid) * DHH;
        const float4* kp0 = (const float4*)kr0;
        const float4* kp1 = (const float4*)(kr0 + (size_t)256 * DHH);
        float acc[2][QQ];
#pragma unroll
        for (int u = 0; u < 2; ++u)
#pragma unroll
            for (int q = 0; q < QQ; ++q) acc[u][q] = 0.f;
        // f64 even/odd-j chains (reassociation safe: f64 headroom ~1e-15 vs
        // 2.3e-4 importance gaps; np reference itself uses BLAS order)
        double a64c[2][2] = {{0.0, 0.0}, {0.0, 0.0}};

#define SC_LOAD(KB, JB)                 \
        KB[0][0] = kp0[(JB)];           \
        KB[0][1] = kp0[(JB) + 1];       \
        KB[1][0] = kp1[(JB)];           \
        KB[1][1] = kp1[(JB) + 1];
#define SC_COMPUTE(KB, JB)                                                    \
        _Pragma("unroll")                                                     \
        for (int jj = 0; jj < 2; ++jj) {                                      \
            _Pragma("unroll")                                                 \
            for (int q = 0; q < QQ; ++q) {                                    \
                float4 qv = *(const float4*)(qs + q * DHH + ((JB) + jj) * 4); \
                _Pragma("unroll")                                             \
                for (int u = 0; u < 2; ++u) {                                 \
                    acc[u][q] = fmaf(KB[u][jj].x, qv.x, acc[u][q]);           \
                    acc[u][q] = fmaf(KB[u][jj].y, qv.y, acc[u][q]);           \
                    acc[u][q] = fmaf(KB[u][jj].z, qv.z, acc[u][q]);           \
                    acc[u][q] = fmaf(KB[u][jj].w, qv.w, acc[u][q]);           \
                }                                                             \
            }                                                                 \
            int j = (JB) + jj;                                                \
            _Pragma("unroll")                                                 \
            for (int u = 0; u < 2; ++u) {                                     \
                a64c[u][jj] = fma((double)KB[u][jj].x, q64s[j*4+0], a64c[u][jj]); \
                a64c[u][jj] = fma((double)KB[u][jj].y, q64s[j*4+1], a64c[u][jj]); \
                a64c[u][jj] = fma((double)KB[u][jj].z, q64s[j*4+2], a64c[u][jj]); \
                a64c[u][jj] = fma((double)KB[u][jj].w, q64s[j*4+3], a64c[u][jj]); \
            }                                                                 \
        }

        float4 kA[2][2], kB[2][2];
        SC_LOAD(kA, 0);
        for (int jb = 0; jb < DHH / 4; jb += 4) {
            SC_LOAD(kB, jb + 2);
            SC_COMPUTE(kA, jb);
            if (jb + 4 < DHH / 4) { SC_LOAD(kA, jb + 4); }
            SC_COMPUTE(kB, jb + 2);
        }
#pragma unroll
        for (int q = 0; q < QQ; ++q) {
#pragma unroll
            for (int u = 0; u < 2; ++u) {
                int key = kbase + u * 256 + tid;
                float sv = acc[u][q] / 11.313708498984761f;
                if (key > PP + q) sv += -1e9f;
                attn[((size_t)(bh * QQ + q)) * KK + key] = sv;
            }
        }
#pragma unroll
        for (int u = 0; u < 2; ++u) {
            double a64 = a64c[u][0] + a64c[u][1];
            sc64[(size_t)bh * KK + kbase + u * 256 + tid] = a64 / (double)sqrtf(128.0f);
        }
    } else {
        if (tid >= 16) return;
        const float* krow = kn + ((size_t)bh * QQ + tid) * DHH;
        float acc[QQ];
#pragma unroll
        for (int q = 0; q < QQ; ++q) acc[q] = 0.f;
        for (int j = 0; j < DHH / 4; ++j) {
            float4 kv = ((const float4*)krow)[j];
#pragma unroll
            for (int q = 0; q < QQ; ++q) {
                float4 qv = *(const float4*)(qs + q * DHH + j * 4);
                acc[q] = fmaf(kv.x, qv.x, acc[q]);
                acc[q] = fmaf(kv.y, qv.y, acc[q]);
                acc[q] = fmaf(kv.z, qv.z, acc[q]);
                acc[q] = fmaf(kv.w, qv.w, acc[q]);
            }
        }
        int key = PP + tid;
#pragma unroll
        for (int q = 0; q < QQ; ++q) {
            float sv = acc[q] / 11.313708498984761f;
            if (key > PP + q) sv += -1e9f;
            attn[((size_t)(bh * QQ + q)) * KK + key] = sv;
        }
        double a64 = 0.0;
        const double* kd = k64 + (size_t)(b * QQ + tid) * DD + h * DHH;
        for (int j = 0; j < DHH; ++j) a64 = fma(kd[j], q64s[j], a64);
        sc64[(size_t)bh * KK + key] = a64 / (double)sqrtf(128.0f);
    }
}

// ---------------------------------------------------------------- per-row max / sum(exp) (f32)
__global__ __launch_bounds__(256) void rowstats_kernel(
    const float* __restrict__ attn, float* __restrict__ rowm, float* __restrict__ rowz)
{
    int row = blockIdx.x;
    const float* s = attn + (size_t)row * KK;
    float m = -INFINITY, z = 0.f;
    for (int k = threadIdx.x; k < KK; k += 256) {
        float v = s[k];
        float nm = fmaxf(m, v);
        z = z * expf(m - nm) + expf(v - nm);
        m = nm;
    }
    __shared__ float sm[256], sz[256];
    sm[threadIdx.x] = m; sz[threadIdx.x] = z;
    __syncthreads();
    for (int off = 128; off > 0; off >>= 1) {
        if (threadIdx.x < off) {
            float m1 = sm[threadIdx.x], z1 = sz[threadIdx.x];
            float m2 = sm[threadIdx.x + off], z2 = sz[threadIdx.x + off];
            float nm = fmaxf(m1, m2);
            sm[threadIdx.x] = nm;
            sz[threadIdx.x] = z1 * expf(m1 - nm) + z2 * expf(m2 - nm);
        }
        __syncthreads();
    }
    if (threadIdx.x == 0) { rowm[row] = sm[0]; rowz[row] = sz[0]; }
}

// ---------------------------------------------------------------- per-row max / sum(exp) (f64)
__global__ __launch_bounds__(256) void rowstats64_kernel(
    const double* __restrict__ sc, double* __restrict__ m64, double* __restrict__ z64)
{
    int row = blockIdx.x;
    const double* s = sc + (size_t)row * KK;
    double m = -INFINITY, z = 0.0;
    for (int k = threadIdx.x; k < KK; k += 256) {
        double v = s[k];
        double nm = fmax(m, v);
        z = z * exp(m - nm) + exp(v - nm);
        m = nm;
    }
    __shared__ double sm[256], sz[256];
    sm[threadIdx.x] = m; sz[threadIdx.x] = z;
    __syncthreads();
    for (int off = 128; off > 0; off >>= 1) {
        if (threadIdx.x < off) {
            double m1 = sm[threadIdx.x], z1 = sz[threadIdx.x];
            double m2 = sm[threadIdx.x + off], z2 = sz[threadIdx.x + off];
            double nm = fmax(m1, m2);
            sm[threadIdx.x] = nm;
            sz[threadIdx.x] = z1 * exp(m1 - nm) + z2 * exp(m2 - nm);
        }
        __syncthreads();
    }
    if (threadIdx.x == 0) { m64[row] = sm[0]; z64[row] = sz[0]; }
}

// ---------------------------------------------------------------- importance keys (f64) + rank zero
__global__ __launch_bounds__(256) void impkeys_kernel(
    const double* __restrict__ sc, const double* __restrict__ m64,
    const double* __restrict__ z64, unsigned long long* __restrict__ keys,
    int* __restrict__ rank)
{
    int k = blockIdx.x * 256 + threadIdx.x;
    if (k >= KK) return;
    rank[k] = 0;
    double t = 0.0;
    for (int bh = 0; bh < BH; ++bh)
        t += exp(sc[(size_t)bh * KK + k] - m64[bh]) / z64[bh];
    double imp = t / 32.0;
    if (k == KK - 1) imp = INFINITY;
    unsigned long long bits = (unsigned long long)__double_as_longlong(imp);
    keys[k] = (bits & ~0x3FFFull) | (unsigned long long)k;
}

// ---------------------------------------------------------------- partial rank
__global__ __launch_bounds__(256) void rankpart_kernel(
    const unsigned long long* __restrict__ keys, int* __restrict__ rank)
{
    __shared__ unsigned long long chnk[1026];
    int gid = blockIdx.x * 256 + threadIdx.x;
    int base = blockIdx.y * 1026;
    for (int i = threadIdx.x; i < 1026; i += 256) chnk[i] = keys[base + i];
    __syncthreads();
    if (gid >= KK) return;
    unsigned long long mykey = keys[gid];
    int cnt = 0;
#pragma unroll 6
    for (int i = 0; i < 1026; ++i) cnt += (chnk[i] < mykey) ? 1 : 0;
    atomicAdd(&rank[gid], cnt);
}

// ---------------------------------------------------------------- rank write
__global__ __launch_bounds__(256) void rankwrite_kernel(
    const unsigned long long* __restrict__ keys, const int* __restrict__ rank,
    float* __restrict__ outp)
{
    int gid = blockIdx.x * 256 + threadIdx.x;
    if (gid >= KK) return;
    int r = rank[gid];
    if (r < NPRUNE)
        outp[r] = (float)(unsigned)(keys[gid] & 0x3FFFu);
}

// ---------------------------------------------------------------- PV: pipelined V loads
__global__ __launch_bounds__(256) void pv_kernel(
    float* __restrict__ attn, const float* __restrict__ past_v,
    const float* __restrict__ vn, const float* __restrict__ rowm,
    const float* __restrict__ rowz, float* __restrict__ part)
{
    int bh = blockIdx.x, ch = blockIdx.y;
    int tid = threadIdx.x;
    __shared__ __align__(16) float p[QQ * 256];
    int nk = (ch < 32) ? 256 : 16;
    int kbase = ch * 256;
    if (tid < nk) {
        float sv[QQ];
#pragma unroll
        for (int q = 0; q < QQ; ++q)
            sv[q] = attn[((size_t)(bh * QQ + q)) * KK + kbase + tid];
#pragma unroll
        for (int q = 0; q < QQ; ++q) {
            int row = bh * QQ + q;
            float pv = expf(sv[q] - rowm[row]) / rowz[row];
            attn[((size_t)row) * KK + kbase + tid] = pv;
            p[q * 256 + tid] = pv;
        }
    }
    __syncthreads();

    int dq = tid & 31, q0 = tid >> 5;
    int d4 = dq * 4;
    float4 a0 = make_float4(0, 0, 0, 0), a1 = make_float4(0, 0, 0, 0);
    if (ch < 32) {
        const float* vbase = past_v + ((size_t)bh * PP + kbase) * DHH;

#define PV_LOAD(VB, KOFF)                                                   \
        _Pragma("unroll")                                                   \
        for (int u = 0; u < 8; ++u)                                         \
            VB[u] = *(const float4*)(vbase + (size_t)((KOFF) + u) * DHH + d4);
#define PV_FMA(VB, KOFF)                                                    \
        _Pragma("unroll")                                                   \
        for (int u = 0; u < 8; ++u) {                                       \
            float p0 = p[q0 * 256 + (KOFF) + u];                            \
            float p1 = p[(q0 + 8) * 256 + (KOFF) + u];                      \
            a0.x = fmaf(VB[u].x, p0, a0.x); a0.y = fmaf(VB[u].y, p0, a0.y); \
            a0.z = fmaf(VB[u].z, p0, a0.z); a0.w = fmaf(VB[u].w, p0, a0.w); \
            a1.x = fmaf(VB[u].x, p1, a1.x); a1.y = fmaf(VB[u].y, p1, a1.y); \
            a1.z = fmaf(VB[u].z, p1, a1.z); a1.w = fmaf(VB[u].w, p1, a1.w); \
        }

        float4 vA[8], vB[8];
        PV_LOAD(vA, 0);
        for (int kk = 0; kk < 256; kk += 16) {
            PV_LOAD(vB, kk + 8);
            PV_FMA(vA, kk);
            if (kk + 16 < 256) { PV_LOAD(vA, kk + 16); }
            PV_FMA(vB, kk + 8);
        }
    } else {
        const float* vbase = vn + (size_t)bh * QQ * DHH;
        for (int kk = 0; kk < 16; ++kk) {
            float4 v4 = *(const float4*)(vbase + (size_t)kk * DHH + d4);
            float p0 = p[q0 * 256 + kk];
            float p1 = p[(q0 + 8) * 256 + kk];
            a0.x = fmaf(v4.x, p0, a0.x); a0.y = fmaf(v4.y, p0, a0.y);
            a0.z = fmaf(v4.z, p0, a0.z); a0.w = fmaf(v4.w, p0, a0.w);
            a1.x = fmaf(v4.x, p1, a1.x); a1.y = fmaf(v4.y, p1, a1.y);
            a1.z = fmaf(v4.z, p1, a1.z); a1.w = fmaf(v4.w, p1, a1.w);
        }
    }
    size_t pb = ((size_t)ch * BH + bh) * (QQ * DHH);
    *(float4*)(part + pb + q0 * DHH + d4) = a0;
    *(float4*)(part + pb + (q0 + 8) * DHH + d4) = a1;
}

// ---------------------------------------------------------------- PV reduce
__global__ __launch_bounds__(256) void pv_reduce_kernel(
    const float* __restrict__ part, float* __restrict__ oattn)
{
    int e = blockIdx.x * 256 + threadIdx.x;
    float s = 0.f;
    for (int ch = 0; ch < 33; ++ch) s += part[(size_t)ch * 65536 + e];
    int bh = e >> 11, rem = e & 2047, q = rem >> 7, d = rem & 127;
    int b = bh >> 4, h = bh & 15;
    oattn[((size_t)(b * QQ + q)) * DD + h * DHH + d] = s;
}

// ---------------------------------------------------------------- Wo reduce + residual (64 chunks)
__global__ __launch_bounds__(256) void reduce_wo_kernel(
    const float* __restrict__ part, const float* __restrict__ resid,
    float* __restrict__ hbuf)
{
    int e = blockIdx.x * 256 + threadIdx.x;
    float acc = 0.f;
#pragma unroll 8
    for (int kc = 0; kc < 64; ++kc) acc += part[(size_t)kc * 65536 + e];
    hbuf[e] = resid[e] + acc;
}

// ---------------------------------------------------------------- gate reduce (16 chunks)
__global__ __launch_bounds__(256) void reduce_gate_kernel(
    const float* __restrict__ part, float* __restrict__ act)
{
    int e = blockIdx.x * 256 + threadIdx.x;
    float g = 0.f;
#pragma unroll 8
    for (int kc = 0; kc < 16; ++kc) g += part[(size_t)kc * 180224 + e];
    act[e] = g;
}

// ---------------------------------------------------------------- up reduce + silu (16 chunks)
__global__ __launch_bounds__(256) void reduce_up_silu_kernel(
    const float* __restrict__ part, float* __restrict__ act)
{
    int e = blockIdx.x * 256 + threadIdx.x;
    float u = 0.f;
#pragma unroll 8
    for (int kc = 0; kc < 16; ++kc) u += part[(size_t)(16 + kc) * 180224 + e];
    float g = act[e];
    float sg = g / (1.f + expf(-g));
    act[e] = sg * u;
}

// ---------------------------------------------------------------- down reduce + residual (88 chunks)
__global__ __launch_bounds__(256) void reduce_down_kernel(
    const float* __restrict__ part, const float* __restrict__ hbuf,
    float* __restrict__ out)
{
    int e = blockIdx.x * 256 + threadIdx.x;
    float acc = 0.f;
#pragma unroll 8
    for (int kc = 0; kc < 88; ++kc) acc += part[(size_t)kc * 65536 + e];
    out[e] = hbuf[e] + acc;
}

// ================================================================ launch
extern "C" void kernel_launch(void* const* d_in, const int* in_sizes, int n_in,
                              void* d_out, int out_size, void* d_ws, size_t ws_size,
                              hipStream_t stream)
{
    const float* hidden = (const float*)d_in[0];
    const float* past_k = (const float*)d_in[1];
    const float* past_v = (const float*)d_in[2];
    const float* wq     = (const float*)d_in[3];
    const float* wk     = (const float*)d_in[4];
    const float* wv     = (const float*)d_in[5];
    const float* wo     = (const float*)d_in[6];
    const float* wgate  = (const float*)d_in[7];
    const float* wup    = (const float*)d_in[8];
    const float* wdown  = (const float*)d_in[9];
    const float* n1w    = (const float*)d_in[10];
    const float* n2w    = (const float*)d_in[11];

    float* out_hidden = (float*)d_out;
    float* attn = out_hidden + (size_t)RR * DD;
    float* out_prune = attn + (size_t)BH * QQ * KK;
    float* ws = (float*)d_ws;
    double* f64 = (double*)(ws + OFF_F64);
    double* x64 = f64 + D_X64;
    double* k64 = f64 + D_K64;
    double* q64 = f64 + D_Q64;
    double* m64 = f64 + D_M64;
    double* z64 = f64 + D_Z64;
    double* sc64 = f64 + D_SC;
    unsigned long long* keys = (unsigned long long*)(f64 + D_KEYS);
    int* rank = (int*)(ws + OFF_RANK);
    double* part64 = (double*)(ws + OFF_UNION);

    // 1. rmsnorm1 (f32)
    rmsnorm_kernel<<<dim3(RR), dim3(256), 0, stream>>>(hidden, n1w, ws + OFF_X);

    // 2. QKV projections — C=2, 384 blocks; layout [mat][kc<32][32][2048]
    gemm32c2<64><<<dim3(4, 32, 3), dim3(256), 0, stream>>>(
        ws + OFF_X, wq, wk, wv, ws + OFF_UNION, DD, DD, (size_t)32 * 65536);

    // 3. reduce + RoPE (f32) — column-parallel, 256 blocks
    reduce_qkv_rope<<<dim3(RR, 8), dim3(256), 0, stream>>>(
        ws + OFF_UNION, ws + OFF_QR, ws + OFF_KN, ws + OFF_VN);

    // 3b. mixed-precision importance side-path
    rms32mix_kernel<<<dim3(RR), dim3(64), 0, stream>>>(hidden, n1w, x64);
    proj64_part_kernel<<<dim3(8, 16), dim3(256), 0, stream>>>(x64, wk, wq, part64);
    proj64_reduce_kernel<<<dim3(272), dim3(256), 0, stream>>>(part64, k64, q64);
    rope64_kernel<<<dim3(34), dim3(256), 0, stream>>>(k64, q64);

    // 4. scores (pipelined, f64 fused split-chains) — 544 blocks
    scores_kernel<<<dim3(BH, 17), dim3(256), 0, stream>>>(
        ws + OFF_QR, past_k, ws + OFF_KN, attn, q64, k64, sc64);

    // 5. row stats + importance keys + ranks
    rowstats_kernel<<<dim3(BH * QQ), dim3(256), 0, stream>>>(
        attn, ws + OFF_ROWM, ws + OFF_ROWZ);
    rowstats64_kernel<<<dim3(BH), dim3(256), 0, stream>>>(sc64, m64, z64);
    impkeys_kernel<<<dim3(33), dim3(256), 0, stream>>>(sc64, m64, z64, keys, rank);
    rankpart_kernel<<<dim3(33, 8), dim3(256), 0, stream>>>(keys, rank);
    rankwrite_kernel<<<dim3(33), dim3(256), 0, stream>>>(keys, rank, out_prune);

    // 6. PV (pipelined V; PV partials in UNION)
    pv_kernel<<<dim3(BH, 33), dim3(256), 0, stream>>>(
        attn, past_v, ws + OFF_VN, ws + OFF_ROWM, ws + OFF_ROWZ, ws + OFF_UNION);

    // 7. PV reduce
    pv_reduce_kernel<<<dim3(256), dim3(256), 0, stream>>>(ws + OFF_UNION, ws + OFF_OATTN);

    // 8. Wo GEMM — C=2, 64 k-splits, 256 blocks
    gemm32c2<32><<<dim3(4, 64, 1), dim3(256), 0, stream>>>(
        ws + OFF_OATTN, wo, wo, wo, ws + OFF_UNION, DD, DD, 0);

    // 9. + residual
    reduce_wo_kernel<<<dim3(256), dim3(256), 0, stream>>>(ws + OFF_UNION, hidden, ws + OFF_H);

    // 10. rmsnorm2
    rmsnorm_kernel<<<dim3(RR), dim3(256), 0, stream>>>(ws + OFF_H, n2w, ws + OFF_Y);

    // 11. gate+up GEMM — C=2, 352 blocks; layout [2][kc<16][32][5632]
    gemm32c2<128><<<dim3(11, 16, 2), dim3(256), 0, stream>>>(
        ws + OFF_Y, wgate, wup, wup, ws + OFF_UNION, DD, FF, (size_t)16 * 180224);
    reduce_gate_kernel<<<dim3(704), dim3(256), 0, stream>>>(ws + OFF_UNION, ws + OFF_ACT);
    reduce_up_silu_kernel<<<dim3(704), dim3(256), 0, stream>>>(ws + OFF_UNION, ws + OFF_ACT);

    // 12. down GEMM — C=2, 88 k-splits, 352 blocks
    gemm32c2<64><<<dim3(4, 88, 1), dim3(256), 0, stream>>>(
        ws + OFF_ACT, wdown, wdown, wdown, ws + OFF_UNION, FF, DD, 0);
    reduce_down_kernel<<<dim3(256), dim3(256), 0, stream>>>(
        ws + OFF_UNION, ws + OFF_H, out_hidden);
}

// Round 15
// 380.169 us; speedup vs baseline: 1.1354x; 1.1354x over previous
//
#include <hip/hip_runtime.h>
#include <math.h>

// Problem constants
#define BB 2
#define QQ 16
#define DD 2048
#define HH 16
#define DHH 128
#define PP 8192
#define FF 5632
#define KK 8208
#define BH 32
#define RR 32      // B*Q rows
#define NPRUNE 820

// Workspace layout (float offsets). ws_size ~512 MiB.
#define OFF_X      0u
#define OFF_QR     65536u
#define OFF_KN     131072u
#define OFF_VN     196608u
#define OFF_ROWM   262144u
#define OFF_ROWZ   262656u
#define OFF_OATTN  263168u
#define OFF_H      328704u
#define OFF_Y      394240u
#define OFF_ACT    459776u
#define OFF_UNION  640064u      // partial region, reused sequentially:
                                //   QKV partials [0, 12582912) (step 2, dies step 3)
                                //   f64 proj partials [0, 4456448) (step 3b)
                                //   PV partials [0, 2162688) (steps 6-7)
                                //   wo partials [0, 4194304) (steps 8-9)
                                //   gate/up partials [0, 11534336) (step 11)
                                //   down partials [0, 11534336) (step 12)
// f64 scalar area lives past the proj64 partial extent; written step 3b,
// fully consumed by step 5 (rankwrite) — before wo/gate/down partials reach it.
#define OFF_F64    (OFF_UNION + 4456448u)
#define D_X64      0u
#define D_K64      65536u
#define D_Q64      131072u
#define D_M64      135168u
#define D_Z64      135200u
#define D_SC       135232u
#define D_KEYS     397888u
#define OFF_RANK   (OFF_F64 + 812192u)

// ---------------------------------------------------------------- rmsnorm (f32 main path)
__global__ __launch_bounds__(256) void rmsnorm_kernel(
    const float* __restrict__ in, const float* __restrict__ w,
    float* __restrict__ out)
{
    int r = blockIdx.x;
    const float* x = in + (size_t)r * DD;
    float ss = 0.f;
    for (int c = threadIdx.x; c < DD; c += 256) { float v = x[c]; ss = fmaf(v, v, ss); }
    __shared__ float red[256];
    red[threadIdx.x] = ss;
    __syncthreads();
    for (int off = 128; off > 0; off >>= 1) {
        if (threadIdx.x < off) red[threadIdx.x] += red[threadIdx.x + off];
        __syncthreads();
    }
    float mean = red[0] / (float)DD;
    float scale = 1.0f / sqrtf(mean + 1e-5f);
    for (int c = threadIdx.x; c < DD; c += 256)
        out[(size_t)r * DD + c] = x[c] * scale * w[c];
}

// ---------------------------------------------------------------- mixed-precision rmsnorm for importance path
__global__ __launch_bounds__(64) void rms32mix_kernel(
    const float* __restrict__ in, const float* __restrict__ w,
    double* __restrict__ out)
{
    int r = blockIdx.x;
    const float* x = in + (size_t)r * DD;
    __shared__ float bs[16];
    __shared__ float sscale;
    int tid = threadIdx.x;
    if (tid < 16) {
        const float* a = x + tid * 128;
        float rr[8];
#pragma unroll
        for (int j = 0; j < 8; ++j) { float v = a[j]; rr[j] = __fmul_rn(v, v); }
        for (int i = 8; i < 128; i += 8) {
#pragma unroll
            for (int j = 0; j < 8; ++j) {
                float v = a[i + j];
                rr[j] = __fadd_rn(rr[j], __fmul_rn(v, v));
            }
        }
        float t01 = __fadd_rn(rr[0], rr[1]);
        float t23 = __fadd_rn(rr[2], rr[3]);
        float t45 = __fadd_rn(rr[4], rr[5]);
        float t67 = __fadd_rn(rr[6], rr[7]);
        bs[tid] = __fadd_rn(__fadd_rn(t01, t23), __fadd_rn(t45, t67));
    }
    __syncthreads();
    if (tid == 0) {
        float c[8], d[4], e[2];
#pragma unroll
        for (int i = 0; i < 8; ++i) c[i] = __fadd_rn(bs[2 * i], bs[2 * i + 1]);
#pragma unroll
        for (int i = 0; i < 4; ++i) d[i] = __fadd_rn(c[2 * i], c[2 * i + 1]);
        e[0] = __fadd_rn(d[0], d[1]);
        e[1] = __fadd_rn(d[2], d[3]);
        float s = __fadd_rn(e[0], e[1]);
        float v = __fdiv_rn(s, 2048.0f);
        float ve = __fadd_rn(v, 1e-5f);
        float sq = __fsqrt_rn(ve);
        sscale = __fdiv_rn(1.0f, sq);
    }
    __syncthreads();
    double scd = (double)sscale;
    for (int c = tid; c < DD; c += 64)
        out[(size_t)r * DD + c] = ((double)x[c] * scd) * (double)w[c];
}

// ---------------------------------------------------------------- f64 K/Q projection, 32 k-splits (256 blocks)
__global__ __launch_bounds__(256) void proj64_part_kernel(
    const double* __restrict__ x64, const float* __restrict__ wk,
    const float* __restrict__ wq, double* __restrict__ part)
{
    int cc = blockIdx.x, kc = blockIdx.y;
    int tid = threadIdx.x;
    int col = cc * 256 + tid;
    int d0 = kc * 64;
    __shared__ double xs[34 * 64];
    for (int i = tid; i < 34 * 64; i += 256) {
        int r = i >> 6, d = i & 63;
        int srcrow = (r < 32) ? r : ((r == 32) ? 15 : 31);
        xs[i] = x64[(size_t)srcrow * DD + d0 + d];
    }
    __syncthreads();
    double acc[34];
#pragma unroll
    for (int r = 0; r < 34; ++r) acc[r] = 0.0;
    const float* wkp = wk + (size_t)d0 * DD + col;
    const float* wqp = wq + (size_t)d0 * DD + col;
    for (int d = 0; d < 64; d += 4) {
        double wkb[4], wqb[4];
#pragma unroll
        for (int u = 0; u < 4; ++u) {
            wkb[u] = (double)wkp[(size_t)(d + u) * DD];
            wqb[u] = (double)wqp[(size_t)(d + u) * DD];
        }
#pragma unroll
        for (int u = 0; u < 4; ++u) {
#pragma unroll
            for (int r = 0; r < 32; ++r) acc[r] = fma(xs[r * 64 + d + u], wkb[u], acc[r]);
            acc[32] = fma(xs[32 * 64 + d + u], wqb[u], acc[32]);
            acc[33] = fma(xs[33 * 64 + d + u], wqb[u], acc[33]);
        }
    }
#pragma unroll
    for (int r = 0; r < 34; ++r)
        part[((size_t)kc * 34 + r) * DD + col] = acc[r];
}

// ---------------------------------------------------------------- f64 projection reduce (32 chunks) -> k64, q64
__global__ __launch_bounds__(256) void proj64_reduce_kernel(
    const double* __restrict__ part, double* __restrict__ k64,
    double* __restrict__ q64)
{
    int e = blockIdx.x * 256 + threadIdx.x;
    if (e >= 34 * DD) return;
    int r = e >> 11, col = e & 2047;
    double s = 0.0;
#pragma unroll 8
    for (int kc = 0; kc < 32; ++kc) s += part[((size_t)kc * 34 + r) * DD + col];
    if (r < 32) k64[(size_t)r * DD + col] = s;
    else        q64[(size_t)(r - 32) * DD + col] = s;
}

// ---------------------------------------------------------------- RoPE with f32-replicated tables, f64 rotation
__global__ __launch_bounds__(256) void rope64_kernel(
    double* __restrict__ k64, double* __restrict__ q64)
{
    int r = blockIdx.x;
    double* row;
    int pos;
    if (r < 32) { row = k64 + (size_t)r * DD; pos = PP + (r & 15); }
    else        { row = q64 + (size_t)(r - 32) * DD; pos = PP + 15; }
#pragma unroll 4
    for (int i = 0; i < 4; ++i) {
        int p = threadIdx.x + 256 * i;
        int h = p >> 6, j = p & 63;
        float pf = (float)pow(10000.0, (double)j / 64.0);
        float invf = __fdiv_rn(1.0f, pf);
        float ang = __fmul_rn((float)pos, invf);
        float cs = (float)cos((double)ang);
        float sn = (float)sin((double)ang);
        int c1 = h * DHH + j, c2 = c1 + 64;
        double v1 = row[c1], v2 = row[c2];
        row[c1] = v1 * (double)cs - v2 * (double)sn;
        row[c2] = v2 * (double)cs + v1 * (double)sn;
    }
}

// ---------------------------------------------------------------- 32-row GEMM, 2 cols/thread, k-split partials
// (round-13 non-pipelined body: load 8-deep W stage, then FMA; LDS via float4)
template<int DCHUNK>
__global__ __launch_bounds__(256) void gemm32c2(
    const float* __restrict__ A, const float* __restrict__ w0,
    const float* __restrict__ w1, const float* __restrict__ w2,
    float* __restrict__ part, int Kdim, int N, size_t zstride)
{
    int cc = blockIdx.x, kc = blockIdx.y, z = blockIdx.z;
    int tid = threadIdx.x;
    int col0 = cc * 512 + tid;
    int d0 = kc * DCHUNK;
    const float* W = (z == 0) ? w0 : (z == 1) ? w1 : w2;
    __shared__ __align__(16) float xs[32 * DCHUNK];
    for (int i = tid; i < 32 * DCHUNK; i += 256) {
        int r = i / DCHUNK, d = i - r * DCHUNK;
        xs[i] = A[(size_t)r * Kdim + d0 + d];
    }
    __syncthreads();
    float acc0[32], acc1[32];
#pragma unroll
    for (int r = 0; r < 32; ++r) { acc0[r] = 0.f; acc1[r] = 0.f; }
    const float* wp = W + (size_t)d0 * N + col0;
    for (int d = 0; d < DCHUNK; d += 8) {
        float wb0[8], wb1[8];
#pragma unroll
        for (int u = 0; u < 8; ++u) {
            wb0[u] = wp[(size_t)(d + u) * N];
            wb1[u] = wp[(size_t)(d + u) * N + 256];
        }
#pragma unroll
        for (int r = 0; r < 32; ++r) {
            const float4 x0 = *(const float4*)(xs + r * DCHUNK + d);
            const float4 x1 = *(const float4*)(xs + r * DCHUNK + d + 4);
            float a = acc0[r], b = acc1[r];
            a = fmaf(x0.x, wb0[0], a);  b = fmaf(x0.x, wb1[0], b);
            a = fmaf(x0.y, wb0[1], a);  b = fmaf(x0.y, wb1[1], b);
            a = fmaf(x0.z, wb0[2], a);  b = fmaf(x0.z, wb1[2], b);
            a = fmaf(x0.w, wb0[3], a);  b = fmaf(x0.w, wb1[3], b);
            a = fmaf(x1.x, wb0[4], a);  b = fmaf(x1.x, wb1[4], b);
            a = fmaf(x1.y, wb0[5], a);  b = fmaf(x1.y, wb1[5], b);
            a = fmaf(x1.z, wb0[6], a);  b = fmaf(x1.z, wb1[6], b);
            a = fmaf(x1.w, wb0[7], a);  b = fmaf(x1.w, wb1[7], b);
            acc0[r] = a; acc1[r] = b;
        }
    }
    float* dst = part + (size_t)z * zstride;
#pragma unroll
    for (int r = 0; r < 32; ++r) {
        dst[((size_t)(kc * 32 + r)) * N + col0] = acc0[r];
        dst[((size_t)(kc * 32 + r)) * N + col0 + 256] = acc1[r];
    }
}

// ---------------------------------------------------------------- QKV reduce + RoPE, column-parallel (64 chunks)
__global__ __launch_bounds__(256) void reduce_qkv_rope(
    const float* __restrict__ part, float* __restrict__ qr,
    float* __restrict__ kn, float* __restrict__ vn)
{
    int r = blockIdx.x;
    int b = r >> 4, qi = r & 15;
    int tid = threadIdx.x;
    int c = blockIdx.y * 256 + tid;
    int h = c >> 7, dh = c & 127, j = dh & 63;

    float invf = (float)exp(-((double)j / 64.0) * log(10000.0));
    float ang = (float)(PP + qi) * invf;
    float sn, cs;
    sincosf(ang, &sn, &cs);

    __shared__ float buf[256];
    size_t dsti = (((size_t)(b * HH + h)) * QQ + qi) * DHH + dh;
    for (int mat = 0; mat < 3; ++mat) {
        const float* pm = part + (size_t)mat * 64 * 65536 + (size_t)r * DD + c;
        float s = 0.f;
#pragma unroll 8
        for (int kc = 0; kc < 64; ++kc)
            s += pm[(size_t)kc * 32 * DD];
        buf[tid] = s;
        __syncthreads();
        float val;
        if (mat == 2) {
            val = s;
        } else {
            float other = (dh < 64) ? -buf[tid + 64] : buf[tid - 64];
            val = s * cs + other * sn;
        }
        float* dst = (mat == 0) ? qr : (mat == 1) ? kn : vn;
        dst[dsti] = val;
        __syncthreads();
    }
}

// ---------------------------------------------------------------- scores: 2 K-rows/thread, f64 fused (K read ONCE)
__global__ __launch_bounds__(256) void scores_kernel(
    const float* __restrict__ qr, const float* __restrict__ past_k,
    const float* __restrict__ kn, float* __restrict__ attn,
    const double* __restrict__ q64, const double* __restrict__ k64,
    double* __restrict__ sc64)
{
    int bh = blockIdx.x, ch = blockIdx.y;
    int b = bh >> 4, h = bh & 15;
    int tid = threadIdx.x;
    __shared__ __align__(16) float qs[QQ * DHH];
    __shared__ double q64s[DHH];
    for (int i = tid; i < QQ * DHH; i += 256) qs[i] = qr[(size_t)bh * (QQ * DHH) + i];
    if (tid < DHH) q64s[tid] = q64[(size_t)b * DD + h * DHH + tid];
    __syncthreads();

    if (ch < 16) {
        int kbase = ch * 512;
        const float* kr0 = past_k + ((size_t)bh * PP + kbase + tid) * DHH;
        float acc[2][QQ];
#pragma unroll
        for (int u = 0; u < 2; ++u)
#pragma unroll
            for (int q = 0; q < QQ; ++q) acc[u][q] = 0.f;
        double a64[2] = {0.0, 0.0};

        for (int jb = 0; jb < DHH / 4; jb += 2) {
            float4 kb[2][2];
#pragma unroll
            for (int u = 0; u < 2; ++u) {
                const float4* kp = (const float4*)(kr0 + (size_t)u * 256 * DHH);
                kb[u][0] = kp[jb];
                kb[u][1] = kp[jb + 1];
            }
#pragma unroll
            for (int jj = 0; jj < 2; ++jj) {
#pragma unroll
                for (int q = 0; q < QQ; ++q) {
                    float4 qv = *(const float4*)(qs + q * DHH + (jb + jj) * 4);
#pragma unroll
                    for (int u = 0; u < 2; ++u) {
                        acc[u][q] = fmaf(kb[u][jj].x, qv.x, acc[u][q]);
                        acc[u][q] = fmaf(kb[u][jj].y, qv.y, acc[u][q]);
                        acc[u][q] = fmaf(kb[u][jj].z, qv.z, acc[u][q]);
                        acc[u][q] = fmaf(kb[u][jj].w, qv.w, acc[u][q]);
                    }
                }
            }
            // f64 chain fused on the already-loaded registers; per key, j runs
            // sequentially with the same x,y,z,w order -> bit-identical.
#pragma unroll
            for (int jj = 0; jj < 2; ++jj) {
                int j = jb + jj;
#pragma unroll
                for (int u = 0; u < 2; ++u) {
                    a64[u] = fma((double)kb[u][jj].x, q64s[j * 4 + 0], a64[u]);
                    a64[u] = fma((double)kb[u][jj].y, q64s[j * 4 + 1], a64[u]);
                    a64[u] = fma((double)kb[u][jj].z, q64s[j * 4 + 2], a64[u]);
                    a64[u] = fma((double)kb[u][jj].w, q64s[j * 4 + 3], a64[u]);
                }
            }
        }
#pragma unroll
        for (int q = 0; q < QQ; ++q) {
#pragma unroll
            for (int u = 0; u < 2; ++u) {
                int key = kbase + u * 256 + tid;
                float sv = acc[u][q] / 11.313708498984761f;
                if (key > PP + q) sv += -1e9f;
                attn[((size_t)(bh * QQ + q)) * KK + key] = sv;
            }
        }
#pragma unroll
        for (int u = 0; u < 2; ++u)
            sc64[(size_t)bh * KK + kbase + u * 256 + tid] = a64[u] / (double)sqrtf(128.0f);
    } else {
        if (tid >= 16) return;
        const float* krow = kn + ((size_t)bh * QQ + tid) * DHH;
        float acc[QQ];
#pragma unroll
        for (int q = 0; q < QQ; ++q) acc[q] = 0.f;
        for (int j = 0; j < DHH / 4; ++j) {
            float4 kv = ((const float4*)krow)[j];
#pragma unroll
            for (int q = 0; q < QQ; ++q) {
                float4 qv = *(const float4*)(qs + q * DHH + j * 4);
                acc[q] = fmaf(kv.x, qv.x, acc[q]);
                acc[q] = fmaf(kv.y, qv.y, acc[q]);
                acc[q] = fmaf(kv.z, qv.z, acc[q]);
                acc[q] = fmaf(kv.w, qv.w, acc[q]);
            }
        }
        int key = PP + tid;
#pragma unroll
        for (int q = 0; q < QQ; ++q) {
            float sv = acc[q] / 11.313708498984761f;
            if (key > PP + q) sv += -1e9f;
            attn[((size_t)(bh * QQ + q)) * KK + key] = sv;
        }
        double a64 = 0.0;
        const double* kd = k64 + (size_t)(b * QQ + tid) * DD + h * DHH;
        for (int j = 0; j < DHH; ++j) a64 = fma(kd[j], q64s[j], a64);
        sc64[(size_t)bh * KK + key] = a64 / (double)sqrtf(128.0f);
    }
}

// ---------------------------------------------------------------- per-row max / sum(exp) (f32)
__global__ __launch_bounds__(256) void rowstats_kernel(
    const float* __restrict__ attn, float* __restrict__ rowm, float* __restrict__ rowz)
{
    int row = blockIdx.x;
    const float* s = attn + (size_t)row * KK;
    float m = -INFINITY, z = 0.f;
    for (int k = threadIdx.x; k < KK; k += 256) {
        float v = s[k];
        float nm = fmaxf(m, v);
        z = z * expf(m - nm) + expf(v - nm);
        m = nm;
    }
    __shared__ float sm[256], sz[256];
    sm[threadIdx.x] = m; sz[threadIdx.x] = z;
    __syncthreads();
    for (int off = 128; off > 0; off >>= 1) {
        if (threadIdx.x < off) {
            float m1 = sm[threadIdx.x], z1 = sz[threadIdx.x];
            float m2 = sm[threadIdx.x + off], z2 = sz[threadIdx.x + off];
            float nm = fmaxf(m1, m2);
            sm[threadIdx.x] = nm;
            sz[threadIdx.x] = z1 * expf(m1 - nm) + z2 * expf(m2 - nm);
        }
        __syncthreads();
    }
    if (threadIdx.x == 0) { rowm[row] = sm[0]; rowz[row] = sz[0]; }
}

// ---------------------------------------------------------------- per-row max / sum(exp) (f64)
__global__ __launch_bounds__(256) void rowstats64_kernel(
    const double* __restrict__ sc, double* __restrict__ m64, double* __restrict__ z64)
{
    int row = blockIdx.x;
    const double* s = sc + (size_t)row * KK;
    double m = -INFINITY, z = 0.0;
    for (int k = threadIdx.x; k < KK; k += 256) {
        double v = s[k];
        double nm = fmax(m, v);
        z = z * exp(m - nm) + exp(v - nm);
        m = nm;
    }
    __shared__ double sm[256], sz[256];
    sm[threadIdx.x] = m; sz[threadIdx.x] = z;
    __syncthreads();
    for (int off = 128; off > 0; off >>= 1) {
        if (threadIdx.x < off) {
            double m1 = sm[threadIdx.x], z1 = sz[threadIdx.x];
            double m2 = sm[threadIdx.x + off], z2 = sz[threadIdx.x + off];
            double nm = fmax(m1, m2);
            sm[threadIdx.x] = nm;
            sz[threadIdx.x] = z1 * exp(m1 - nm) + z2 * exp(m2 - nm);
        }
        __syncthreads();
    }
    if (threadIdx.x == 0) { m64[row] = sm[0]; z64[row] = sz[0]; }
}

// ---------------------------------------------------------------- importance keys (f64) + rank zero
__global__ __launch_bounds__(256) void impkeys_kernel(
    const double* __restrict__ sc, const double* __restrict__ m64,
    const double* __restrict__ z64, unsigned long long* __restrict__ keys,
    int* __restrict__ rank)
{
    int k = blockIdx.x * 256 + threadIdx.x;
    if (k >= KK) return;
    rank[k] = 0;
    double t = 0.0;
    for (int bh = 0; bh < BH; ++bh)
        t += exp(sc[(size_t)bh * KK + k] - m64[bh]) / z64[bh];
    double imp = t / 32.0;
    if (k == KK - 1) imp = INFINITY;
    unsigned long long bits = (unsigned long long)__double_as_longlong(imp);
    keys[k] = (bits & ~0x3FFFull) | (unsigned long long)k;
}

// ---------------------------------------------------------------- partial rank
__global__ __launch_bounds__(256) void rankpart_kernel(
    const unsigned long long* __restrict__ keys, int* __restrict__ rank)
{
    __shared__ unsigned long long chnk[1026];
    int gid = blockIdx.x * 256 + threadIdx.x;
    int base = blockIdx.y * 1026;
    for (int i = threadIdx.x; i < 1026; i += 256) chnk[i] = keys[base + i];
    __syncthreads();
    if (gid >= KK) return;
    unsigned long long mykey = keys[gid];
    int cnt = 0;
#pragma unroll 6
    for (int i = 0; i < 1026; ++i) cnt += (chnk[i] < mykey) ? 1 : 0;
    atomicAdd(&rank[gid], cnt);
}

// ---------------------------------------------------------------- rank write
__global__ __launch_bounds__(256) void rankwrite_kernel(
    const unsigned long long* __restrict__ keys, const int* __restrict__ rank,
    float* __restrict__ outp)
{
    int gid = blockIdx.x * 256 + threadIdx.x;
    if (gid >= KK) return;
    int r = rank[gid];
    if (r < NPRUNE)
        outp[r] = (float)(unsigned)(keys[gid] & 0x3FFFu);
}

// ---------------------------------------------------------------- PV: normalize attn in place + O partials
__global__ __launch_bounds__(256) void pv_kernel(
    float* __restrict__ attn, const float* __restrict__ past_v,
    const float* __restrict__ vn, const float* __restrict__ rowm,
    const float* __restrict__ rowz, float* __restrict__ part)
{
    int bh = blockIdx.x, ch = blockIdx.y;
    int tid = threadIdx.x;
    __shared__ __align__(16) float p[QQ * 256];
    int nk = (ch < 32) ? 256 : 16;
    int kbase = ch * 256;
    if (tid < nk) {
        float sv[QQ];
#pragma unroll
        for (int q = 0; q < QQ; ++q)
            sv[q] = attn[((size_t)(bh * QQ + q)) * KK + kbase + tid];
#pragma unroll
        for (int q = 0; q < QQ; ++q) {
            int row = bh * QQ + q;
            float pv = expf(sv[q] - rowm[row]) / rowz[row];
            attn[((size_t)row) * KK + kbase + tid] = pv;
            p[q * 256 + tid] = pv;
        }
    }
    __syncthreads();

    int dq = tid & 31, q0 = tid >> 5;
    int d4 = dq * 4;
    float4 a0 = make_float4(0, 0, 0, 0), a1 = make_float4(0, 0, 0, 0);
    if (ch < 32) {
        const float* vbase = past_v + ((size_t)bh * PP + kbase) * DHH;
        for (int kk = 0; kk < 256; kk += 8) {
            float4 vb[8];
#pragma unroll
            for (int u = 0; u < 8; ++u)
                vb[u] = *(const float4*)(vbase + (size_t)(kk + u) * DHH + d4);
#pragma unroll
            for (int u = 0; u < 8; ++u) {
                float p0 = p[q0 * 256 + kk + u];
                float p1 = p[(q0 + 8) * 256 + kk + u];
                a0.x = fmaf(vb[u].x, p0, a0.x); a0.y = fmaf(vb[u].y, p0, a0.y);
                a0.z = fmaf(vb[u].z, p0, a0.z); a0.w = fmaf(vb[u].w, p0, a0.w);
                a1.x = fmaf(vb[u].x, p1, a1.x); a1.y = fmaf(vb[u].y, p1, a1.y);
                a1.z = fmaf(vb[u].z, p1, a1.z); a1.w = fmaf(vb[u].w, p1, a1.w);
            }
        }
    } else {
        const float* vbase = vn + (size_t)bh * QQ * DHH;
        for (int kk = 0; kk < 16; ++kk) {
            float4 v4 = *(const float4*)(vbase + (size_t)kk * DHH + d4);
            float p0 = p[q0 * 256 + kk];
            float p1 = p[(q0 + 8) * 256 + kk];
            a0.x = fmaf(v4.x, p0, a0.x); a0.y = fmaf(v4.y, p0, a0.y);
            a0.z = fmaf(v4.z, p0, a0.z); a0.w = fmaf(v4.w, p0, a0.w);
            a1.x = fmaf(v4.x, p1, a1.x); a1.y = fmaf(v4.y, p1, a1.y);
            a1.z = fmaf(v4.z, p1, a1.z); a1.w = fmaf(v4.w, p1, a1.w);
        }
    }
    size_t pb = ((size_t)ch * BH + bh) * (QQ * DHH);
    *(float4*)(part + pb + q0 * DHH + d4) = a0;
    *(float4*)(part + pb + (q0 + 8) * DHH + d4) = a1;
}

// ---------------------------------------------------------------- PV reduce
__global__ __launch_bounds__(256) void pv_reduce_kernel(
    const float* __restrict__ part, float* __restrict__ oattn)
{
    int e = blockIdx.x * 256 + threadIdx.x;
    float s = 0.f;
    for (int ch = 0; ch < 33; ++ch) s += part[(size_t)ch * 65536 + e];
    int bh = e >> 11, rem = e & 2047, q = rem >> 7, d = rem & 127;
    int b = bh >> 4, h = bh & 15;
    oattn[((size_t)(b * QQ + q)) * DD + h * DHH + d] = s;
}

// ---------------------------------------------------------------- Wo reduce + residual (64 chunks)
__global__ __launch_bounds__(256) void reduce_wo_kernel(
    const float* __restrict__ part, const float* __restrict__ resid,
    float* __restrict__ hbuf)
{
    int e = blockIdx.x * 256 + threadIdx.x;
    float acc = 0.f;
#pragma unroll 8
    for (int kc = 0; kc < 64; ++kc) acc += part[(size_t)kc * 65536 + e];
    hbuf[e] = resid[e] + acc;
}

// ---------------------------------------------------------------- gate reduce (32 chunks)
__global__ __launch_bounds__(256) void reduce_gate_kernel(
    const float* __restrict__ part, float* __restrict__ act)
{
    int e = blockIdx.x * 256 + threadIdx.x;
    float g = 0.f;
#pragma unroll 8
    for (int kc = 0; kc < 32; ++kc) g += part[(size_t)kc * 180224 + e];
    act[e] = g;
}

// ---------------------------------------------------------------- up reduce + silu (32 chunks)
__global__ __launch_bounds__(256) void reduce_up_silu_kernel(
    const float* __restrict__ part, float* __restrict__ act)
{
    int e = blockIdx.x * 256 + threadIdx.x;
    float u = 0.f;
#pragma unroll 8
    for (int kc = 0; kc < 32; ++kc) u += part[(size_t)(32 + kc) * 180224 + e];
    float g = act[e];
    float sg = g / (1.f + expf(-g));
    act[e] = sg * u;
}

// ---------------------------------------------------------------- down reduce + residual (176 chunks)
__global__ __launch_bounds__(256) void reduce_down_kernel(
    const float* __restrict__ part, const float* __restrict__ hbuf,
    float* __restrict__ out)
{
    int e = blockIdx.x * 256 + threadIdx.x;
    float acc = 0.f;
#pragma unroll 8
    for (int kc = 0; kc < 176; ++kc) acc += part[(size_t)kc * 65536 + e];
    out[e] = hbuf[e] + acc;
}

// ================================================================ launch
extern "C" void kernel_launch(void* const* d_in, const int* in_sizes, int n_in,
                              void* d_out, int out_size, void* d_ws, size_t ws_size,
                              hipStream_t stream)
{
    const float* hidden = (const float*)d_in[0];
    const float* past_k = (const float*)d_in[1];
    const float* past_v = (const float*)d_in[2];
    const float* wq     = (const float*)d_in[3];
    const float* wk     = (const float*)d_in[4];
    const float* wv     = (const float*)d_in[5];
    const float* wo     = (const float*)d_in[6];
    const float* wgate  = (const float*)d_in[7];
    const float* wup    = (const float*)d_in[8];
    const float* wdown  = (const float*)d_in[9];
    const float* n1w    = (const float*)d_in[10];
    const float* n2w    = (const float*)d_in[11];

    float* out_hidden = (float*)d_out;
    float* attn = out_hidden + (size_t)RR * DD;
    float* out_prune = attn + (size_t)BH * QQ * KK;
    float* ws = (float*)d_ws;
    double* f64 = (double*)(ws + OFF_F64);
    double* x64 = f64 + D_X64;
    double* k64 = f64 + D_K64;
    double* q64 = f64 + D_Q64;
    double* m64 = f64 + D_M64;
    double* z64 = f64 + D_Z64;
    double* sc64 = f64 + D_SC;
    unsigned long long* keys = (unsigned long long*)(f64 + D_KEYS);
    int* rank = (int*)(ws + OFF_RANK);
    double* part64 = (double*)(ws + OFF_UNION);

    // 1. rmsnorm1 (f32)
    rmsnorm_kernel<<<dim3(RR), dim3(256), 0, stream>>>(hidden, n1w, ws + OFF_X);

    // 2. QKV projections — C=2, 64 k-splits, 768 blocks; layout [mat][kc<64][32][2048]
    gemm32c2<32><<<dim3(4, 64, 3), dim3(256), 0, stream>>>(
        ws + OFF_X, wq, wk, wv, ws + OFF_UNION, DD, DD, (size_t)64 * 65536);

    // 3. reduce + RoPE (f32) — column-parallel, 256 blocks, 64 chunks
    reduce_qkv_rope<<<dim3(RR, 8), dim3(256), 0, stream>>>(
        ws + OFF_UNION, ws + OFF_QR, ws + OFF_KN, ws + OFF_VN);

    // 3b. mixed-precision importance side-path — proj64 now 256 blocks
    rms32mix_kernel<<<dim3(RR), dim3(64), 0, stream>>>(hidden, n1w, x64);
    proj64_part_kernel<<<dim3(8, 32), dim3(256), 0, stream>>>(x64, wk, wq, part64);
    proj64_reduce_kernel<<<dim3(272), dim3(256), 0, stream>>>(part64, k64, q64);
    rope64_kernel<<<dim3(34), dim3(256), 0, stream>>>(k64, q64);

    // 4. scores (f32 + fused f64, K read once) — 544 blocks
    scores_kernel<<<dim3(BH, 17), dim3(256), 0, stream>>>(
        ws + OFF_QR, past_k, ws + OFF_KN, attn, q64, k64, sc64);

    // 5. row stats + importance keys + ranks (f64 area fully consumed here)
    rowstats_kernel<<<dim3(BH * QQ), dim3(256), 0, stream>>>(
        attn, ws + OFF_ROWM, ws + OFF_ROWZ);
    rowstats64_kernel<<<dim3(BH), dim3(256), 0, stream>>>(sc64, m64, z64);
    impkeys_kernel<<<dim3(33), dim3(256), 0, stream>>>(sc64, m64, z64, keys, rank);
    rankpart_kernel<<<dim3(33, 8), dim3(256), 0, stream>>>(keys, rank);
    rankwrite_kernel<<<dim3(33), dim3(256), 0, stream>>>(keys, rank, out_prune);

    // 6. PV (normalizes attn in place; PV partials in UNION)
    pv_kernel<<<dim3(BH, 33), dim3(256), 0, stream>>>(
        attn, past_v, ws + OFF_VN, ws + OFF_ROWM, ws + OFF_ROWZ, ws + OFF_UNION);

    // 7. PV reduce
    pv_reduce_kernel<<<dim3(256), dim3(256), 0, stream>>>(ws + OFF_UNION, ws + OFF_OATTN);

    // 8. Wo GEMM — C=2, 64 k-splits, 256 blocks
    gemm32c2<32><<<dim3(4, 64, 1), dim3(256), 0, stream>>>(
        ws + OFF_OATTN, wo, wo, wo, ws + OFF_UNION, DD, DD, 0);

    // 9. + residual
    reduce_wo_kernel<<<dim3(256), dim3(256), 0, stream>>>(ws + OFF_UNION, hidden, ws + OFF_H);

    // 10. rmsnorm2
    rmsnorm_kernel<<<dim3(RR), dim3(256), 0, stream>>>(ws + OFF_H, n2w, ws + OFF_Y);

    // 11. gate+up GEMM — C=2, 32 k-splits, 704 blocks; layout [2][kc<32][32][5632]
    gemm32c2<64><<<dim3(11, 32, 2), dim3(256), 0, stream>>>(
        ws + OFF_Y, wgate, wup, wup, ws + OFF_UNION, DD, FF, (size_t)32 * 180224);
    reduce_gate_kernel<<<dim3(704), dim3(256), 0, stream>>>(ws + OFF_UNION, ws + OFF_ACT);
    reduce_up_silu_kernel<<<dim3(704), dim3(256), 0, stream>>>(ws + OFF_UNION, ws + OFF_ACT);

    // 12. down GEMM — C=2, 176 k-splits, 704 blocks
    gemm32c2<32><<<dim3(4, 176, 1), dim3(256), 0, stream>>>(
        ws + OFF_ACT, wdown, wdown, wdown, ws + OFF_UNION, FF, DD, 0);
    reduce_down_kernel<<<dim3(256), dim3(256), 0, stream>>>(
        ws + OFF_UNION, ws + OFF_H, out_hidden);
}

// Round 16
// 379.754 us; speedup vs baseline: 1.1366x; 1.0011x over previous
//
#include <hip/hip_runtime.h>
#include <math.h>

// Problem constants
#define BB 2
#define QQ 16
#define DD 2048
#define HH 16
#define DHH 128
#define PP 8192
#define FF 5632
#define KK 8208
#define BH 32
#define RR 32      // B*Q rows
#define NPRUNE 820

// Workspace layout (float offsets). ws_size ~512 MiB.
#define OFF_X      0u
#define OFF_QR     65536u
#define OFF_KN     131072u
#define OFF_VN     196608u
#define OFF_ROWM   262144u
#define OFF_ROWZ   262656u
#define OFF_OATTN  263168u
#define OFF_H      328704u
#define OFF_Y      394240u
#define OFF_ACT    459776u
#define OFF_UNION  640064u      // partial region, reused sequentially (see r15 audit)
#define OFF_F64    (OFF_UNION + 4456448u)
#define D_X64      0u
#define D_K64      65536u
#define D_Q64      131072u
#define D_M64      135168u
#define D_Z64      135200u
#define D_SC       135232u
#define D_KEYS     397888u
#define OFF_RANK   (OFF_F64 + 812192u)

// ---------------------------------------------------------------- rmsnorm (f32 main path)
__global__ __launch_bounds__(256) void rmsnorm_kernel(
    const float* __restrict__ in, const float* __restrict__ w,
    float* __restrict__ out)
{
    int r = blockIdx.x;
    const float* x = in + (size_t)r * DD;
    float ss = 0.f;
    for (int c = threadIdx.x; c < DD; c += 256) { float v = x[c]; ss = fmaf(v, v, ss); }
    __shared__ float red[256];
    red[threadIdx.x] = ss;
    __syncthreads();
    for (int off = 128; off > 0; off >>= 1) {
        if (threadIdx.x < off) red[threadIdx.x] += red[threadIdx.x + off];
        __syncthreads();
    }
    float mean = red[0] / (float)DD;
    float scale = 1.0f / sqrtf(mean + 1e-5f);
    for (int c = threadIdx.x; c < DD; c += 256)
        out[(size_t)r * DD + c] = x[c] * scale * w[c];
}

// ---------------------------------------------------------------- mixed-precision rmsnorm for importance path
__global__ __launch_bounds__(64) void rms32mix_kernel(
    const float* __restrict__ in, const float* __restrict__ w,
    double* __restrict__ out)
{
    int r = blockIdx.x;
    const float* x = in + (size_t)r * DD;
    __shared__ float bs[16];
    __shared__ float sscale;
    int tid = threadIdx.x;
    if (tid < 16) {
        const float* a = x + tid * 128;
        float rr[8];
#pragma unroll
        for (int j = 0; j < 8; ++j) { float v = a[j]; rr[j] = __fmul_rn(v, v); }
        for (int i = 8; i < 128; i += 8) {
#pragma unroll
            for (int j = 0; j < 8; ++j) {
                float v = a[i + j];
                rr[j] = __fadd_rn(rr[j], __fmul_rn(v, v));
            }
        }
        float t01 = __fadd_rn(rr[0], rr[1]);
        float t23 = __fadd_rn(rr[2], rr[3]);
        float t45 = __fadd_rn(rr[4], rr[5]);
        float t67 = __fadd_rn(rr[6], rr[7]);
        bs[tid] = __fadd_rn(__fadd_rn(t01, t23), __fadd_rn(t45, t67));
    }
    __syncthreads();
    if (tid == 0) {
        float c[8], d[4], e[2];
#pragma unroll
        for (int i = 0; i < 8; ++i) c[i] = __fadd_rn(bs[2 * i], bs[2 * i + 1]);
#pragma unroll
        for (int i = 0; i < 4; ++i) d[i] = __fadd_rn(c[2 * i], c[2 * i + 1]);
        e[0] = __fadd_rn(d[0], d[1]);
        e[1] = __fadd_rn(d[2], d[3]);
        float s = __fadd_rn(e[0], e[1]);
        float v = __fdiv_rn(s, 2048.0f);
        float ve = __fadd_rn(v, 1e-5f);
        float sq = __fsqrt_rn(ve);
        sscale = __fdiv_rn(1.0f, sq);
    }
    __syncthreads();
    double scd = (double)sscale;
    for (int c = tid; c < DD; c += 64)
        out[(size_t)r * DD + c] = ((double)x[c] * scd) * (double)w[c];
}

// ---------------------------------------------------------------- f64 K/Q projection, 32 k-splits (256 blocks)
__global__ __launch_bounds__(256) void proj64_part_kernel(
    const double* __restrict__ x64, const float* __restrict__ wk,
    const float* __restrict__ wq, double* __restrict__ part)
{
    int cc = blockIdx.x, kc = blockIdx.y;
    int tid = threadIdx.x;
    int col = cc * 256 + tid;
    int d0 = kc * 64;
    __shared__ double xs[34 * 64];
    for (int i = tid; i < 34 * 64; i += 256) {
        int r = i >> 6, d = i & 63;
        int srcrow = (r < 32) ? r : ((r == 32) ? 15 : 31);
        xs[i] = x64[(size_t)srcrow * DD + d0 + d];
    }
    __syncthreads();
    double acc[34];
#pragma unroll
    for (int r = 0; r < 34; ++r) acc[r] = 0.0;
    const float* wkp = wk + (size_t)d0 * DD + col;
    const float* wqp = wq + (size_t)d0 * DD + col;
    for (int d = 0; d < 64; d += 4) {
        double wkb[4], wqb[4];
#pragma unroll
        for (int u = 0; u < 4; ++u) {
            wkb[u] = (double)wkp[(size_t)(d + u) * DD];
            wqb[u] = (double)wqp[(size_t)(d + u) * DD];
        }
#pragma unroll
        for (int u = 0; u < 4; ++u) {
#pragma unroll
            for (int r = 0; r < 32; ++r) acc[r] = fma(xs[r * 64 + d + u], wkb[u], acc[r]);
            acc[32] = fma(xs[32 * 64 + d + u], wqb[u], acc[32]);
            acc[33] = fma(xs[33 * 64 + d + u], wqb[u], acc[33]);
        }
    }
#pragma unroll
    for (int r = 0; r < 34; ++r)
        part[((size_t)kc * 34 + r) * DD + col] = acc[r];
}

// ---------------------------------------------------------------- f64 projection reduce (32 chunks) -> k64, q64
__global__ __launch_bounds__(256) void proj64_reduce_kernel(
    const double* __restrict__ part, double* __restrict__ k64,
    double* __restrict__ q64)
{
    int e = blockIdx.x * 256 + threadIdx.x;
    if (e >= 34 * DD) return;
    int r = e >> 11, col = e & 2047;
    double s = 0.0;
#pragma unroll 8
    for (int kc = 0; kc < 32; ++kc) s += part[((size_t)kc * 34 + r) * DD + col];
    if (r < 32) k64[(size_t)r * DD + col] = s;
    else        q64[(size_t)(r - 32) * DD + col] = s;
}

// ---------------------------------------------------------------- RoPE with f32-replicated tables, f64 rotation
__global__ __launch_bounds__(256) void rope64_kernel(
    double* __restrict__ k64, double* __restrict__ q64)
{
    int r = blockIdx.x;
    double* row;
    int pos;
    if (r < 32) { row = k64 + (size_t)r * DD; pos = PP + (r & 15); }
    else        { row = q64 + (size_t)(r - 32) * DD; pos = PP + 15; }
#pragma unroll 4
    for (int i = 0; i < 4; ++i) {
        int p = threadIdx.x + 256 * i;
        int h = p >> 6, j = p & 63;
        float pf = (float)pow(10000.0, (double)j / 64.0);
        float invf = __fdiv_rn(1.0f, pf);
        float ang = __fmul_rn((float)pos, invf);
        float cs = (float)cos((double)ang);
        float sn = (float)sin((double)ang);
        int c1 = h * DHH + j, c2 = c1 + 64;
        double v1 = row[c1], v2 = row[c2];
        row[c1] = v1 * (double)cs - v2 * (double)sn;
        row[c2] = v2 * (double)cs + v1 * (double)sn;
    }
}

// ---------------------------------------------------------------- 32-row GEMM, 2 cols/thread, k-split partials
template<int DCHUNK>
__global__ __launch_bounds__(256) void gemm32c2(
    const float* __restrict__ A, const float* __restrict__ w0,
    const float* __restrict__ w1, const float* __restrict__ w2,
    float* __restrict__ part, int Kdim, int N, size_t zstride)
{
    int cc = blockIdx.x, kc = blockIdx.y, z = blockIdx.z;
    int tid = threadIdx.x;
    int col0 = cc * 512 + tid;
    int d0 = kc * DCHUNK;
    const float* W = (z == 0) ? w0 : (z == 1) ? w1 : w2;
    __shared__ __align__(16) float xs[32 * DCHUNK];
    for (int i = tid; i < 32 * DCHUNK; i += 256) {
        int r = i / DCHUNK, d = i - r * DCHUNK;
        xs[i] = A[(size_t)r * Kdim + d0 + d];
    }
    __syncthreads();
    float acc0[32], acc1[32];
#pragma unroll
    for (int r = 0; r < 32; ++r) { acc0[r] = 0.f; acc1[r] = 0.f; }
    const float* wp = W + (size_t)d0 * N + col0;
    for (int d = 0; d < DCHUNK; d += 8) {
        float wb0[8], wb1[8];
#pragma unroll
        for (int u = 0; u < 8; ++u) {
            wb0[u] = wp[(size_t)(d + u) * N];
            wb1[u] = wp[(size_t)(d + u) * N + 256];
        }
#pragma unroll
        for (int r = 0; r < 32; ++r) {
            const float4 x0 = *(const float4*)(xs + r * DCHUNK + d);
            const float4 x1 = *(const float4*)(xs + r * DCHUNK + d + 4);
            float a = acc0[r], b = acc1[r];
            a = fmaf(x0.x, wb0[0], a);  b = fmaf(x0.x, wb1[0], b);
            a = fmaf(x0.y, wb0[1], a);  b = fmaf(x0.y, wb1[1], b);
            a = fmaf(x0.z, wb0[2], a);  b = fmaf(x0.z, wb1[2], b);
            a = fmaf(x0.w, wb0[3], a);  b = fmaf(x0.w, wb1[3], b);
            a = fmaf(x1.x, wb0[4], a);  b = fmaf(x1.x, wb1[4], b);
            a = fmaf(x1.y, wb0[5], a);  b = fmaf(x1.y, wb1[5], b);
            a = fmaf(x1.z, wb0[6], a);  b = fmaf(x1.z, wb1[6], b);
            a = fmaf(x1.w, wb0[7], a);  b = fmaf(x1.w, wb1[7], b);
            acc0[r] = a; acc1[r] = b;
        }
    }
    float* dst = part + (size_t)z * zstride;
#pragma unroll
    for (int r = 0; r < 32; ++r) {
        dst[((size_t)(kc * 32 + r)) * N + col0] = acc0[r];
        dst[((size_t)(kc * 32 + r)) * N + col0 + 256] = acc1[r];
    }
}

// ---------------------------------------------------------------- QKV reduce + RoPE, column-parallel, dual streams
__global__ __launch_bounds__(256) void reduce_qkv_rope(
    const float* __restrict__ part, float* __restrict__ qr,
    float* __restrict__ kn, float* __restrict__ vn)
{
    int r = blockIdx.x;
    int b = r >> 4, qi = r & 15;
    int tid = threadIdx.x;
    int c = blockIdx.y * 256 + tid;
    int h = c >> 7, dh = c & 127, j = dh & 63;

    float invf = (float)exp(-((double)j / 64.0) * log(10000.0));
    float ang = (float)(PP + qi) * invf;
    float sn, cs;
    sincosf(ang, &sn, &cs);

    __shared__ float buf[256];
    size_t dsti = (((size_t)(b * HH + h)) * QQ + qi) * DHH + dh;
    for (int mat = 0; mat < 3; ++mat) {
        const float* pm = part + (size_t)mat * 64 * 65536 + (size_t)r * DD + c;
        float sa = 0.f, sb = 0.f;   // two independent streams (2x in-flight)
#pragma unroll 8
        for (int kc = 0; kc < 32; ++kc) {
            sa += pm[(size_t)kc * 32 * DD];
            sb += pm[(size_t)(kc + 32) * 32 * DD];
        }
        float s = sa + sb;
        buf[tid] = s;
        __syncthreads();
        float val;
        if (mat == 2) {
            val = s;
        } else {
            float other = (dh < 64) ? -buf[tid + 64] : buf[tid - 64];
            val = s * cs + other * sn;
        }
        float* dst = (mat == 0) ? qr : (mat == 1) ? kn : vn;
        dst[dsti] = val;
        __syncthreads();
    }
}

// ---------------------------------------------------------------- scores: 2 K-rows/thread, f64 fused (K read ONCE)
__global__ __launch_bounds__(256) void scores_kernel(
    const float* __restrict__ qr, const float* __restrict__ past_k,
    const float* __restrict__ kn, float* __restrict__ attn,
    const double* __restrict__ q64, const double* __restrict__ k64,
    double* __restrict__ sc64)
{
    int bh = blockIdx.x, ch = blockIdx.y;
    int b = bh >> 4, h = bh & 15;
    int tid = threadIdx.x;
    __shared__ __align__(16) float qs[QQ * DHH];
    __shared__ double q64s[DHH];
    for (int i = tid; i < QQ * DHH; i += 256) qs[i] = qr[(size_t)bh * (QQ * DHH) + i];
    if (tid < DHH) q64s[tid] = q64[(size_t)b * DD + h * DHH + tid];
    __syncthreads();

    if (ch < 16) {
        int kbase = ch * 512;
        const float* kr0 = past_k + ((size_t)bh * PP + kbase + tid) * DHH;
        float acc[2][QQ];
#pragma unroll
        for (int u = 0; u < 2; ++u)
#pragma unroll
            for (int q = 0; q < QQ; ++q) acc[u][q] = 0.f;
        double a64[2] = {0.0, 0.0};

        for (int jb = 0; jb < DHH / 4; jb += 2) {
            float4 kb[2][2];
#pragma unroll
            for (int u = 0; u < 2; ++u) {
                const float4* kp = (const float4*)(kr0 + (size_t)u * 256 * DHH);
                kb[u][0] = kp[jb];
                kb[u][1] = kp[jb + 1];
            }
#pragma unroll
            for (int jj = 0; jj < 2; ++jj) {
#pragma unroll
                for (int q = 0; q < QQ; ++q) {
                    float4 qv = *(const float4*)(qs + q * DHH + (jb + jj) * 4);
#pragma unroll
                    for (int u = 0; u < 2; ++u) {
                        acc[u][q] = fmaf(kb[u][jj].x, qv.x, acc[u][q]);
                        acc[u][q] = fmaf(kb[u][jj].y, qv.y, acc[u][q]);
                        acc[u][q] = fmaf(kb[u][jj].z, qv.z, acc[u][q]);
                        acc[u][q] = fmaf(kb[u][jj].w, qv.w, acc[u][q]);
                    }
                }
            }
#pragma unroll
            for (int jj = 0; jj < 2; ++jj) {
                int j = jb + jj;
#pragma unroll
                for (int u = 0; u < 2; ++u) {
                    a64[u] = fma((double)kb[u][jj].x, q64s[j * 4 + 0], a64[u]);
                    a64[u] = fma((double)kb[u][jj].y, q64s[j * 4 + 1], a64[u]);
                    a64[u] = fma((double)kb[u][jj].z, q64s[j * 4 + 2], a64[u]);
                    a64[u] = fma((double)kb[u][jj].w, q64s[j * 4 + 3], a64[u]);
                }
            }
        }
#pragma unroll
        for (int q = 0; q < QQ; ++q) {
#pragma unroll
            for (int u = 0; u < 2; ++u) {
                int key = kbase + u * 256 + tid;
                float sv = acc[u][q] / 11.313708498984761f;
                if (key > PP + q) sv += -1e9f;
                attn[((size_t)(bh * QQ + q)) * KK + key] = sv;
            }
        }
#pragma unroll
        for (int u = 0; u < 2; ++u)
            sc64[(size_t)bh * KK + kbase + u * 256 + tid] = a64[u] / (double)sqrtf(128.0f);
    } else {
        if (tid >= 16) return;
        const float* krow = kn + ((size_t)bh * QQ + tid) * DHH;
        float acc[QQ];
#pragma unroll
        for (int q = 0; q < QQ; ++q) acc[q] = 0.f;
        for (int j = 0; j < DHH / 4; ++j) {
            float4 kv = ((const float4*)krow)[j];
#pragma unroll
            for (int q = 0; q < QQ; ++q) {
                float4 qv = *(const float4*)(qs + q * DHH + j * 4);
                acc[q] = fmaf(kv.x, qv.x, acc[q]);
                acc[q] = fmaf(kv.y, qv.y, acc[q]);
                acc[q] = fmaf(kv.z, qv.z, acc[q]);
                acc[q] = fmaf(kv.w, qv.w, acc[q]);
            }
        }
        int key = PP + tid;
#pragma unroll
        for (int q = 0; q < QQ; ++q) {
            float sv = acc[q] / 11.313708498984761f;
            if (key > PP + q) sv += -1e9f;
            attn[((size_t)(bh * QQ + q)) * KK + key] = sv;
        }
        double a64 = 0.0;
        const double* kd = k64 + (size_t)(b * QQ + tid) * DD + h * DHH;
        for (int j = 0; j < DHH; ++j) a64 = fma(kd[j], q64s[j], a64);
        sc64[(size_t)bh * KK + key] = a64 / (double)sqrtf(128.0f);
    }
}

// ---------------------------------------------------------------- per-row max / sum(exp) (f32)
__global__ __launch_bounds__(256) void rowstats_kernel(
    const float* __restrict__ attn, float* __restrict__ rowm, float* __restrict__ rowz)
{
    int row = blockIdx.x;
    const float* s = attn + (size_t)row * KK;
    float m = -INFINITY, z = 0.f;
    for (int k = threadIdx.x; k < KK; k += 256) {
        float v = s[k];
        float nm = fmaxf(m, v);
        z = z * expf(m - nm) + expf(v - nm);
        m = nm;
    }
    __shared__ float sm[256], sz[256];
    sm[threadIdx.x] = m; sz[threadIdx.x] = z;
    __syncthreads();
    for (int off = 128; off > 0; off >>= 1) {
        if (threadIdx.x < off) {
            float m1 = sm[threadIdx.x], z1 = sz[threadIdx.x];
            float m2 = sm[threadIdx.x + off], z2 = sz[threadIdx.x + off];
            float nm = fmaxf(m1, m2);
            sm[threadIdx.x] = nm;
            sz[threadIdx.x] = z1 * expf(m1 - nm) + z2 * expf(m2 - nm);
        }
        __syncthreads();
    }
    if (threadIdx.x == 0) { rowm[row] = sm[0]; rowz[row] = sz[0]; }
}

// ---------------------------------------------------------------- per-row max / sum(exp) (f64)
__global__ __launch_bounds__(256) void rowstats64_kernel(
    const double* __restrict__ sc, double* __restrict__ m64, double* __restrict__ z64)
{
    int row = blockIdx.x;
    const double* s = sc + (size_t)row * KK;
    double m = -INFINITY, z = 0.0;
    for (int k = threadIdx.x; k < KK; k += 256) {
        double v = s[k];
        double nm = fmax(m, v);
        z = z * exp(m - nm) + exp(v - nm);
        m = nm;
    }
    __shared__ double sm[256], sz[256];
    sm[threadIdx.x] = m; sz[threadIdx.x] = z;
    __syncthreads();
    for (int off = 128; off > 0; off >>= 1) {
        if (threadIdx.x < off) {
            double m1 = sm[threadIdx.x], z1 = sz[threadIdx.x];
            double m2 = sm[threadIdx.x + off], z2 = sz[threadIdx.x + off];
            double nm = fmax(m1, m2);
            sm[threadIdx.x] = nm;
            sz[threadIdx.x] = z1 * exp(m1 - nm) + z2 * exp(m2 - nm);
        }
        __syncthreads();
    }
    if (threadIdx.x == 0) { m64[row] = sm[0]; z64[row] = sz[0]; }
}

// ---------------------------------------------------------------- importance keys (f64) + rank zero
__global__ __launch_bounds__(256) void impkeys_kernel(
    const double* __restrict__ sc, const double* __restrict__ m64,
    const double* __restrict__ z64, unsigned long long* __restrict__ keys,
    int* __restrict__ rank)
{
    int k = blockIdx.x * 256 + threadIdx.x;
    if (k >= KK) return;
    rank[k] = 0;
    double t = 0.0;
    for (int bh = 0; bh < BH; ++bh)
        t += exp(sc[(size_t)bh * KK + k] - m64[bh]) / z64[bh];
    double imp = t / 32.0;
    if (k == KK - 1) imp = INFINITY;
    unsigned long long bits = (unsigned long long)__double_as_longlong(imp);
    keys[k] = (bits & ~0x3FFFull) | (unsigned long long)k;
}

// ---------------------------------------------------------------- partial rank
__global__ __launch_bounds__(256) void rankpart_kernel(
    const unsigned long long* __restrict__ keys, int* __restrict__ rank)
{
    __shared__ unsigned long long chnk[1026];
    int gid = blockIdx.x * 256 + threadIdx.x;
    int base = blockIdx.y * 1026;
    for (int i = threadIdx.x; i < 1026; i += 256) chnk[i] = keys[base + i];
    __syncthreads();
    if (gid >= KK) return;
    unsigned long long mykey = keys[gid];
    int cnt = 0;
#pragma unroll 6
    for (int i = 0; i < 1026; ++i) cnt += (chnk[i] < mykey) ? 1 : 0;
    atomicAdd(&rank[gid], cnt);
}

// ---------------------------------------------------------------- rank write
__global__ __launch_bounds__(256) void rankwrite_kernel(
    const unsigned long long* __restrict__ keys, const int* __restrict__ rank,
    float* __restrict__ outp)
{
    int gid = blockIdx.x * 256 + threadIdx.x;
    if (gid >= KK) return;
    int r = rank[gid];
    if (r < NPRUNE)
        outp[r] = (float)(unsigned)(keys[gid] & 0x3FFFu);
}

// ---------------------------------------------------------------- PV: normalize attn in place + O partials
__global__ __launch_bounds__(256) void pv_kernel(
    float* __restrict__ attn, const float* __restrict__ past_v,
    const float* __restrict__ vn, const float* __restrict__ rowm,
    const float* __restrict__ rowz, float* __restrict__ part)
{
    int bh = blockIdx.x, ch = blockIdx.y;
    int tid = threadIdx.x;
    __shared__ __align__(16) float p[QQ * 256];
    int nk = (ch < 32) ? 256 : 16;
    int kbase = ch * 256;
    if (tid < nk) {
        float sv[QQ];
#pragma unroll
        for (int q = 0; q < QQ; ++q)
            sv[q] = attn[((size_t)(bh * QQ + q)) * KK + kbase + tid];
#pragma unroll
        for (int q = 0; q < QQ; ++q) {
            int row = bh * QQ + q;
            float pv = expf(sv[q] - rowm[row]) / rowz[row];
            attn[((size_t)row) * KK + kbase + tid] = pv;
            p[q * 256 + tid] = pv;
        }
    }
    __syncthreads();

    int dq = tid & 31, q0 = tid >> 5;
    int d4 = dq * 4;
    float4 a0 = make_float4(0, 0, 0, 0), a1 = make_float4(0, 0, 0, 0);
    if (ch < 32) {
        const float* vbase = past_v + ((size_t)bh * PP + kbase) * DHH;
        for (int kk = 0; kk < 256; kk += 8) {
            float4 vb[8];
#pragma unroll
            for (int u = 0; u < 8; ++u)
                vb[u] = *(const float4*)(vbase + (size_t)(kk + u) * DHH + d4);
#pragma unroll
            for (int u = 0; u < 8; ++u) {
                float p0 = p[q0 * 256 + kk + u];
                float p1 = p[(q0 + 8) * 256 + kk + u];
                a0.x = fmaf(vb[u].x, p0, a0.x); a0.y = fmaf(vb[u].y, p0, a0.y);
                a0.z = fmaf(vb[u].z, p0, a0.z); a0.w = fmaf(vb[u].w, p0, a0.w);
                a1.x = fmaf(vb[u].x, p1, a1.x); a1.y = fmaf(vb[u].y, p1, a1.y);
                a1.z = fmaf(vb[u].z, p1, a1.z); a1.w = fmaf(vb[u].w, p1, a1.w);
            }
        }
    } else {
        const float* vbase = vn + (size_t)bh * QQ * DHH;
        for (int kk = 0; kk < 16; ++kk) {
            float4 v4 = *(const float4*)(vbase + (size_t)kk * DHH + d4);
            float p0 = p[q0 * 256 + kk];
            float p1 = p[(q0 + 8) * 256 + kk];
            a0.x = fmaf(v4.x, p0, a0.x); a0.y = fmaf(v4.y, p0, a0.y);
            a0.z = fmaf(v4.z, p0, a0.z); a0.w = fmaf(v4.w, p0, a0.w);
            a1.x = fmaf(v4.x, p1, a1.x); a1.y = fmaf(v4.y, p1, a1.y);
            a1.z = fmaf(v4.z, p1, a1.z); a1.w = fmaf(v4.w, p1, a1.w);
        }
    }
    size_t pb = ((size_t)ch * BH + bh) * (QQ * DHH);
    *(float4*)(part + pb + q0 * DHH + d4) = a0;
    *(float4*)(part + pb + (q0 + 8) * DHH + d4) = a1;
}

// ---------------------------------------------------------------- PV reduce (dual streams: 16 + 17 chunks)
__global__ __launch_bounds__(256) void pv_reduce_kernel(
    const float* __restrict__ part, float* __restrict__ oattn)
{
    int e = blockIdx.x * 256 + threadIdx.x;
    float sa = 0.f, sb = 0.f;
#pragma unroll 8
    for (int ch = 0; ch < 16; ++ch) sa += part[(size_t)ch * 65536 + e];
#pragma unroll 8
    for (int ch = 16; ch < 33; ++ch) sb += part[(size_t)ch * 65536 + e];
    float s = sa + sb;
    int bh = e >> 11, rem = e & 2047, q = rem >> 7, d = rem & 127;
    int b = bh >> 4, h = bh & 15;
    oattn[((size_t)(b * QQ + q)) * DD + h * DHH + d] = s;
}

// ---------------------------------------------------------------- Wo reduce + residual (dual 32+32)
__global__ __launch_bounds__(256) void reduce_wo_kernel(
    const float* __restrict__ part, const float* __restrict__ resid,
    float* __restrict__ hbuf)
{
    int e = blockIdx.x * 256 + threadIdx.x;
    float sa = 0.f, sb = 0.f;
#pragma unroll 8
    for (int kc = 0; kc < 32; ++kc) {
        sa += part[(size_t)kc * 65536 + e];
        sb += part[(size_t)(kc + 32) * 65536 + e];
    }
    hbuf[e] = resid[e] + (sa + sb);
}

// ---------------------------------------------------------------- fused gate+up reduce + silu (dual streams each)
__global__ __launch_bounds__(256) void reduce_gateup_silu_kernel(
    const float* __restrict__ part, float* __restrict__ act)
{
    int e = blockIdx.x * 256 + threadIdx.x;
    float ga = 0.f, gb = 0.f, ua = 0.f, ub = 0.f;
#pragma unroll 8
    for (int kc = 0; kc < 16; ++kc) {
        ga += part[(size_t)kc * 180224 + e];
        gb += part[(size_t)(kc + 16) * 180224 + e];
        ua += part[(size_t)(kc + 32) * 180224 + e];
        ub += part[(size_t)(kc + 48) * 180224 + e];
    }
    float g = ga + gb, u = ua + ub;
    float sg = g / (1.f + expf(-g));
    act[e] = sg * u;
}

// ---------------------------------------------------------------- down reduce + residual (dual 88+88)
__global__ __launch_bounds__(256) void reduce_down_kernel(
    const float* __restrict__ part, const float* __restrict__ hbuf,
    float* __restrict__ out)
{
    int e = blockIdx.x * 256 + threadIdx.x;
    float sa = 0.f, sb = 0.f;
#pragma unroll 8
    for (int kc = 0; kc < 88; ++kc) {
        sa += part[(size_t)kc * 65536 + e];
        sb += part[(size_t)(kc + 88) * 65536 + e];
    }
    out[e] = hbuf[e] + (sa + sb);
}

// ================================================================ launch
extern "C" void kernel_launch(void* const* d_in, const int* in_sizes, int n_in,
                              void* d_out, int out_size, void* d_ws, size_t ws_size,
                              hipStream_t stream)
{
    const float* hidden = (const float*)d_in[0];
    const float* past_k = (const float*)d_in[1];
    const float* past_v = (const float*)d_in[2];
    const float* wq     = (const float*)d_in[3];
    const float* wk     = (const float*)d_in[4];
    const float* wv     = (const float*)d_in[5];
    const float* wo     = (const float*)d_in[6];
    const float* wgate  = (const float*)d_in[7];
    const float* wup    = (const float*)d_in[8];
    const float* wdown  = (const float*)d_in[9];
    const float* n1w    = (const float*)d_in[10];
    const float* n2w    = (const float*)d_in[11];

    float* out_hidden = (float*)d_out;
    float* attn = out_hidden + (size_t)RR * DD;
    float* out_prune = attn + (size_t)BH * QQ * KK;
    float* ws = (float*)d_ws;
    double* f64 = (double*)(ws + OFF_F64);
    double* x64 = f64 + D_X64;
    double* k64 = f64 + D_K64;
    double* q64 = f64 + D_Q64;
    double* m64 = f64 + D_M64;
    double* z64 = f64 + D_Z64;
    double* sc64 = f64 + D_SC;
    unsigned long long* keys = (unsigned long long*)(f64 + D_KEYS);
    int* rank = (int*)(ws + OFF_RANK);
    double* part64 = (double*)(ws + OFF_UNION);

    // 1. rmsnorm1 (f32)
    rmsnorm_kernel<<<dim3(RR), dim3(256), 0, stream>>>(hidden, n1w, ws + OFF_X);

    // 2. QKV projections — C=2, 64 k-splits, 768 blocks
    gemm32c2<32><<<dim3(4, 64, 3), dim3(256), 0, stream>>>(
        ws + OFF_X, wq, wk, wv, ws + OFF_UNION, DD, DD, (size_t)64 * 65536);

    // 3. reduce + RoPE (f32) — column-parallel, dual streams
    reduce_qkv_rope<<<dim3(RR, 8), dim3(256), 0, stream>>>(
        ws + OFF_UNION, ws + OFF_QR, ws + OFF_KN, ws + OFF_VN);

    // 3b. mixed-precision importance side-path
    rms32mix_kernel<<<dim3(RR), dim3(64), 0, stream>>>(hidden, n1w, x64);
    proj64_part_kernel<<<dim3(8, 32), dim3(256), 0, stream>>>(x64, wk, wq, part64);
    proj64_reduce_kernel<<<dim3(272), dim3(256), 0, stream>>>(part64, k64, q64);
    rope64_kernel<<<dim3(34), dim3(256), 0, stream>>>(k64, q64);

    // 4. scores (f32 + fused f64, K read once) — 544 blocks
    scores_kernel<<<dim3(BH, 17), dim3(256), 0, stream>>>(
        ws + OFF_QR, past_k, ws + OFF_KN, attn, q64, k64, sc64);

    // 5. row stats + importance keys + ranks
    rowstats_kernel<<<dim3(BH * QQ), dim3(256), 0, stream>>>(
        attn, ws + OFF_ROWM, ws + OFF_ROWZ);
    rowstats64_kernel<<<dim3(BH), dim3(256), 0, stream>>>(sc64, m64, z64);
    impkeys_kernel<<<dim3(33), dim3(256), 0, stream>>>(sc64, m64, z64, keys, rank);
    rankpart_kernel<<<dim3(33, 8), dim3(256), 0, stream>>>(keys, rank);
    rankwrite_kernel<<<dim3(33), dim3(256), 0, stream>>>(keys, rank, out_prune);

    // 6. PV (normalizes attn in place; PV partials in UNION)
    pv_kernel<<<dim3(BH, 33), dim3(256), 0, stream>>>(
        attn, past_v, ws + OFF_VN, ws + OFF_ROWM, ws + OFF_ROWZ, ws + OFF_UNION);

    // 7. PV reduce
    pv_reduce_kernel<<<dim3(256), dim3(256), 0, stream>>>(ws + OFF_UNION, ws + OFF_OATTN);

    // 8. Wo GEMM — C=2, 64 k-splits, 256 blocks
    gemm32c2<32><<<dim3(4, 64, 1), dim3(256), 0, stream>>>(
        ws + OFF_OATTN, wo, wo, wo, ws + OFF_UNION, DD, DD, 0);

    // 9. + residual
    reduce_wo_kernel<<<dim3(256), dim3(256), 0, stream>>>(ws + OFF_UNION, hidden, ws + OFF_H);

    // 10. rmsnorm2
    rmsnorm_kernel<<<dim3(RR), dim3(256), 0, stream>>>(ws + OFF_H, n2w, ws + OFF_Y);

    // 11. gate+up GEMM — C=2, 32 k-splits, 704 blocks; fused reduce+silu
    gemm32c2<64><<<dim3(11, 32, 2), dim3(256), 0, stream>>>(
        ws + OFF_Y, wgate, wup, wup, ws + OFF_UNION, DD, FF, (size_t)32 * 180224);
    reduce_gateup_silu_kernel<<<dim3(704), dim3(256), 0, stream>>>(
        ws + OFF_UNION, ws + OFF_ACT);

    // 12. down GEMM — C=2, 176 k-splits, 704 blocks
    gemm32c2<32><<<dim3(4, 176, 1), dim3(256), 0, stream>>>(
        ws + OFF_ACT, wdown, wdown, wdown, ws + OFF_UNION, FF, DD, 0);
    reduce_down_kernel<<<dim3(256), dim3(256), 0, stream>>>(
        ws + OFF_UNION, ws + OFF_H, out_hidden);
}

// Round 17
// 324.226 us; speedup vs baseline: 1.3313x; 1.1713x over previous
//
#include <hip/hip_runtime.h>
#include <math.h>

// Problem constants
#define BB 2
#define QQ 16
#define DD 2048
#define HH 16
#define DHH 128
#define PP 8192
#define FF 5632
#define KK 8208
#define BH 32
#define RR 32      // B*Q rows
#define NPRUNE 820

// Workspace layout (float offsets). ws_size ~512 MiB.
#define OFF_X      0u
#define OFF_QR     65536u
#define OFF_KN     131072u
#define OFF_VN     196608u
#define OFF_ROWM   262144u
#define OFF_ROWZ   262656u
#define OFF_OATTN  263168u
#define OFF_H      328704u
#define OFF_Y      394240u
#define OFF_ACT    459776u
#define OFF_UNION  640064u      // partial region, reused sequentially:
                                //   QKV partials [0, 12582912) (launch 2, dies launch 3)
                                //   PV partials [0, 2162688)
                                //   wo partials [0, 4194304)
                                //   gate/up partials [0, 11534336)
                                //   down partials [0, 11534336)
#define OFF_P64P   (OFF_UNION + 12582912u)  // proj64 partials (launch 2->3), 4456448 floats
#define OFF_F64    (OFF_P64P + 4456448u)    // f64 scalars, consumed by rankwrite
#define D_X64      0u
#define D_K64      65536u
#define D_Q64      131072u
#define D_M64      135168u
#define D_Z64      135200u
#define D_SC       135232u
#define D_KEYS     397888u
#define OFF_RANK   (OFF_F64 + 812192u)

// ---------------------------------------------------------------- rmsnorm (f32, used standalone for norm2)
__global__ __launch_bounds__(256) void rmsnorm_kernel(
    const float* __restrict__ in, const float* __restrict__ w,
    float* __restrict__ out)
{
    int r = blockIdx.x;
    const float* x = in + (size_t)r * DD;
    float ss = 0.f;
    for (int c = threadIdx.x; c < DD; c += 256) { float v = x[c]; ss = fmaf(v, v, ss); }
    __shared__ float red[256];
    red[threadIdx.x] = ss;
    __syncthreads();
    for (int off = 128; off > 0; off >>= 1) {
        if (threadIdx.x < off) red[threadIdx.x] += red[threadIdx.x + off];
        __syncthreads();
    }
    float mean = red[0] / (float)DD;
    float scale = 1.0f / sqrtf(mean + 1e-5f);
    for (int c = threadIdx.x; c < DD; c += 256)
        out[(size_t)r * DD + c] = x[c] * scale * w[c];
}

// ---------------------------------------------------------------- fused: rmsnorm1 (blocks 0-31) + rms32mix (32-63)
__global__ __launch_bounds__(256) void fused_rms_kernel(
    const float* __restrict__ in, const float* __restrict__ w,
    float* __restrict__ out32, double* __restrict__ out64)
{
    int bx = blockIdx.x, tid = threadIdx.x;
    __shared__ float red[256];
    __shared__ float bs[16];
    __shared__ float sscale;
    if (bx < 32) {
        int r = bx;
        const float* x = in + (size_t)r * DD;
        float ss = 0.f;
        for (int c = tid; c < DD; c += 256) { float v = x[c]; ss = fmaf(v, v, ss); }
        red[tid] = ss;
        __syncthreads();
        for (int off = 128; off > 0; off >>= 1) {
            if (tid < off) red[tid] += red[tid + off];
            __syncthreads();
        }
        float mean = red[0] / (float)DD;
        float scale = 1.0f / sqrtf(mean + 1e-5f);
        for (int c = tid; c < DD; c += 256)
            out32[(size_t)r * DD + c] = x[c] * scale * w[c];
    } else {
        int r = bx - 32;
        const float* x = in + (size_t)r * DD;
        if (tid < 16) {
            const float* a = x + tid * 128;
            float rr[8];
#pragma unroll
            for (int j = 0; j < 8; ++j) { float v = a[j]; rr[j] = __fmul_rn(v, v); }
            for (int i = 8; i < 128; i += 8) {
#pragma unroll
                for (int j = 0; j < 8; ++j) {
                    float v = a[i + j];
                    rr[j] = __fadd_rn(rr[j], __fmul_rn(v, v));
                }
            }
            float t01 = __fadd_rn(rr[0], rr[1]);
            float t23 = __fadd_rn(rr[2], rr[3]);
            float t45 = __fadd_rn(rr[4], rr[5]);
            float t67 = __fadd_rn(rr[6], rr[7]);
            bs[tid] = __fadd_rn(__fadd_rn(t01, t23), __fadd_rn(t45, t67));
        }
        __syncthreads();
        if (tid == 0) {
            float c[8], d[4], e[2];
#pragma unroll
            for (int i = 0; i < 8; ++i) c[i] = __fadd_rn(bs[2 * i], bs[2 * i + 1]);
#pragma unroll
            for (int i = 0; i < 4; ++i) d[i] = __fadd_rn(c[2 * i], c[2 * i + 1]);
            e[0] = __fadd_rn(d[0], d[1]);
            e[1] = __fadd_rn(d[2], d[3]);
            float s = __fadd_rn(e[0], e[1]);
            float v = __fdiv_rn(s, 2048.0f);
            float ve = __fadd_rn(v, 1e-5f);
            float sq = __fsqrt_rn(ve);
            sscale = __fdiv_rn(1.0f, sq);
        }
        __syncthreads();
        double scd = (double)sscale;
        for (int c = tid; c < DD; c += 256)
            out64[(size_t)r * DD + c] = ((double)x[c] * scd) * (double)w[c];
    }
}

// ---------------------------------------------------------------- 32-row GEMM, 2 cols/thread (standalone template)
template<int DCHUNK>
__global__ __launch_bounds__(256) void gemm32c2(
    const float* __restrict__ A, const float* __restrict__ w0,
    const float* __restrict__ w1, const float* __restrict__ w2,
    float* __restrict__ part, int Kdim, int N, size_t zstride)
{
    int cc = blockIdx.x, kc = blockIdx.y, z = blockIdx.z;
    int tid = threadIdx.x;
    int col0 = cc * 512 + tid;
    int d0 = kc * DCHUNK;
    const float* W = (z == 0) ? w0 : (z == 1) ? w1 : w2;
    __shared__ __align__(16) float xs[32 * DCHUNK];
    for (int i = tid; i < 32 * DCHUNK; i += 256) {
        int r = i / DCHUNK, d = i - r * DCHUNK;
        xs[i] = A[(size_t)r * Kdim + d0 + d];
    }
    __syncthreads();
    float acc0[32], acc1[32];
#pragma unroll
    for (int r = 0; r < 32; ++r) { acc0[r] = 0.f; acc1[r] = 0.f; }
    const float* wp = W + (size_t)d0 * N + col0;
    for (int d = 0; d < DCHUNK; d += 8) {
        float wb0[8], wb1[8];
#pragma unroll
        for (int u = 0; u < 8; ++u) {
            wb0[u] = wp[(size_t)(d + u) * N];
            wb1[u] = wp[(size_t)(d + u) * N + 256];
        }
#pragma unroll
        for (int r = 0; r < 32; ++r) {
            const float4 x0 = *(const float4*)(xs + r * DCHUNK + d);
            const float4 x1 = *(const float4*)(xs + r * DCHUNK + d + 4);
            float a = acc0[r], b = acc1[r];
            a = fmaf(x0.x, wb0[0], a);  b = fmaf(x0.x, wb1[0], b);
            a = fmaf(x0.y, wb0[1], a);  b = fmaf(x0.y, wb1[1], b);
            a = fmaf(x0.z, wb0[2], a);  b = fmaf(x0.z, wb1[2], b);
            a = fmaf(x0.w, wb0[3], a);  b = fmaf(x0.w, wb1[3], b);
            a = fmaf(x1.x, wb0[4], a);  b = fmaf(x1.x, wb1[4], b);
            a = fmaf(x1.y, wb0[5], a);  b = fmaf(x1.y, wb1[5], b);
            a = fmaf(x1.z, wb0[6], a);  b = fmaf(x1.z, wb1[6], b);
            a = fmaf(x1.w, wb0[7], a);  b = fmaf(x1.w, wb1[7], b);
            acc0[r] = a; acc1[r] = b;
        }
    }
    float* dst = part + (size_t)z * zstride;
#pragma unroll
    for (int r = 0; r < 32; ++r) {
        dst[((size_t)(kc * 32 + r)) * N + col0] = acc0[r];
        dst[((size_t)(kc * 32 + r)) * N + col0 + 256] = acc1[r];
    }
}

// ---------------------------------------------------------------- fused: QKV GEMM (blocks 0-767) + proj64_part (768-1023)
__global__ __launch_bounds__(256) void fused_qkv_p64_kernel(
    const float* __restrict__ A, const float* __restrict__ wq,
    const float* __restrict__ wk, const float* __restrict__ wv,
    float* __restrict__ part, const double* __restrict__ x64,
    double* __restrict__ p64)
{
    int bx = blockIdx.x, tid = threadIdx.x;
    __shared__ __align__(16) float xs[32 * 32];
    __shared__ double xs64[34 * 64];
    if (bx < 768) {
        int cc = bx & 3, kc = (bx >> 2) & 63, z = bx >> 8;
        int col0 = cc * 512 + tid;
        int d0 = kc * 32;
        const float* W = (z == 0) ? wq : (z == 1) ? wk : wv;
        for (int i = tid; i < 32 * 32; i += 256) {
            int r = i >> 5, d = i & 31;
            xs[i] = A[(size_t)r * DD + d0 + d];
        }
        __syncthreads();
        float acc0[32], acc1[32];
#pragma unroll
        for (int r = 0; r < 32; ++r) { acc0[r] = 0.f; acc1[r] = 0.f; }
        const float* wp = W + (size_t)d0 * DD + col0;
        for (int d = 0; d < 32; d += 8) {
            float wb0[8], wb1[8];
#pragma unroll
            for (int u = 0; u < 8; ++u) {
                wb0[u] = wp[(size_t)(d + u) * DD];
                wb1[u] = wp[(size_t)(d + u) * DD + 256];
            }
#pragma unroll
            for (int r = 0; r < 32; ++r) {
                const float4 x0 = *(const float4*)(xs + r * 32 + d);
                const float4 x1 = *(const float4*)(xs + r * 32 + d + 4);
                float a = acc0[r], b = acc1[r];
                a = fmaf(x0.x, wb0[0], a);  b = fmaf(x0.x, wb1[0], b);
                a = fmaf(x0.y, wb0[1], a);  b = fmaf(x0.y, wb1[1], b);
                a = fmaf(x0.z, wb0[2], a);  b = fmaf(x0.z, wb1[2], b);
                a = fmaf(x0.w, wb0[3], a);  b = fmaf(x0.w, wb1[3], b);
                a = fmaf(x1.x, wb0[4], a);  b = fmaf(x1.x, wb1[4], b);
                a = fmaf(x1.y, wb0[5], a);  b = fmaf(x1.y, wb1[5], b);
                a = fmaf(x1.z, wb0[6], a);  b = fmaf(x1.z, wb1[6], b);
                a = fmaf(x1.w, wb0[7], a);  b = fmaf(x1.w, wb1[7], b);
                acc0[r] = a; acc1[r] = b;
            }
        }
        float* dst = part + (size_t)z * 64 * 65536;
#pragma unroll
        for (int r = 0; r < 32; ++r) {
            dst[((size_t)(kc * 32 + r)) * DD + col0] = acc0[r];
            dst[((size_t)(kc * 32 + r)) * DD + col0 + 256] = acc1[r];
        }
    } else {
        int p = bx - 768;
        int cc = p & 7, kc = p >> 3;     // 8 col-chunks x 32 k-splits
        int col = cc * 256 + tid;
        int d0 = kc * 64;
        for (int i = tid; i < 34 * 64; i += 256) {
            int r = i >> 6, d = i & 63;
            int srcrow = (r < 32) ? r : ((r == 32) ? 15 : 31);
            xs64[i] = x64[(size_t)srcrow * DD + d0 + d];
        }
        __syncthreads();
        double acc[34];
#pragma unroll
        for (int r = 0; r < 34; ++r) acc[r] = 0.0;
        const float* wkp = wk + (size_t)d0 * DD + col;
        const float* wqp = wq + (size_t)d0 * DD + col;
        for (int d = 0; d < 64; d += 4) {
            double wkb[4], wqb[4];
#pragma unroll
            for (int u = 0; u < 4; ++u) {
                wkb[u] = (double)wkp[(size_t)(d + u) * DD];
                wqb[u] = (double)wqp[(size_t)(d + u) * DD];
            }
#pragma unroll
            for (int u = 0; u < 4; ++u) {
#pragma unroll
                for (int r = 0; r < 32; ++r) acc[r] = fma(xs64[r * 64 + d + u], wkb[u], acc[r]);
                acc[32] = fma(xs64[32 * 64 + d + u], wqb[u], acc[32]);
                acc[33] = fma(xs64[33 * 64 + d + u], wqb[u], acc[33]);
            }
        }
#pragma unroll
        for (int r = 0; r < 34; ++r)
            p64[((size_t)kc * 34 + r) * DD + col] = acc[r];
    }
}

// ---------------------------------------------------------------- fused: QKV reduce+RoPE (0-255) + proj64 reduce+RoPE (256-527)
__global__ __launch_bounds__(256) void fused_reduce_kernel(
    const float* __restrict__ part, float* __restrict__ qr,
    float* __restrict__ kn, float* __restrict__ vn,
    const double* __restrict__ p64, double* __restrict__ k64,
    double* __restrict__ q64)
{
    int bx = blockIdx.x, tid = threadIdx.x;
    __shared__ float buf[256];
    __shared__ double dbuf[256];
    if (bx < 256) {
        int r = bx >> 3;
        int b = r >> 4, qi = r & 15;
        int c = (bx & 7) * 256 + tid;
        int h = c >> 7, dh = c & 127, j = dh & 63;
        float invf = (float)exp(-((double)j / 64.0) * log(10000.0));
        float ang = (float)(PP + qi) * invf;
        float sn, cs;
        sincosf(ang, &sn, &cs);
        size_t dsti = (((size_t)(b * HH + h)) * QQ + qi) * DHH + dh;
        for (int mat = 0; mat < 3; ++mat) {
            const float* pm = part + (size_t)mat * 64 * 65536 + (size_t)r * DD + c;
            float sa = 0.f, sb = 0.f;
#pragma unroll 8
            for (int kc = 0; kc < 32; ++kc) {
                sa += pm[(size_t)kc * 32 * DD];
                sb += pm[(size_t)(kc + 32) * 32 * DD];
            }
            float s = sa + sb;
            buf[tid] = s;
            __syncthreads();
            float val;
            if (mat == 2) {
                val = s;
            } else {
                float other = (dh < 64) ? -buf[tid + 64] : buf[tid - 64];
                val = s * cs + other * sn;
            }
            float* dst = (mat == 0) ? qr : (mat == 1) ? kn : vn;
            dst[dsti] = val;
            __syncthreads();
        }
    } else {
        int e = (bx - 256) * 256 + tid;   // < 34*2048
        int r = e >> 11, col = e & 2047;
        double s = 0.0;
#pragma unroll 8
        for (int kc = 0; kc < 32; ++kc) s += p64[((size_t)kc * 34 + r) * DD + col];
        dbuf[tid] = s;
        __syncthreads();
        int dh = col & 127, j = dh & 63;
        int pos = (r < 32) ? (PP + (r & 15)) : (PP + 15);
        float pf = (float)pow(10000.0, (double)j / 64.0);
        float invf = __fdiv_rn(1.0f, pf);
        float ang = __fmul_rn((float)pos, invf);
        float cs = (float)cos((double)ang);
        float sn = (float)sin((double)ang);
        double outv;
        if (dh < 64) outv = s * (double)cs - dbuf[tid + 64] * (double)sn;
        else         outv = s * (double)cs + dbuf[tid - 64] * (double)sn;
        if (r < 32) k64[(size_t)r * DD + col] = outv;
        else        q64[(size_t)(r - 32) * DD + col] = outv;
    }
}

// ---------------------------------------------------------------- scores: 2 K-rows/thread, f64 fused (K read ONCE)
__global__ __launch_bounds__(256) void scores_kernel(
    const float* __restrict__ qr, const float* __restrict__ past_k,
    const float* __restrict__ kn, float* __restrict__ attn,
    const double* __restrict__ q64, const double* __restrict__ k64,
    double* __restrict__ sc64)
{
    int bh = blockIdx.x, ch = blockIdx.y;
    int b = bh >> 4, h = bh & 15;
    int tid = threadIdx.x;
    __shared__ __align__(16) float qs[QQ * DHH];
    __shared__ double q64s[DHH];
    for (int i = tid; i < QQ * DHH; i += 256) qs[i] = qr[(size_t)bh * (QQ * DHH) + i];
    if (tid < DHH) q64s[tid] = q64[(size_t)b * DD + h * DHH + tid];
    __syncthreads();

    if (ch < 16) {
        int kbase = ch * 512;
        const float* kr0 = past_k + ((size_t)bh * PP + kbase + tid) * DHH;
        float acc[2][QQ];
#pragma unroll
        for (int u = 0; u < 2; ++u)
#pragma unroll
            for (int q = 0; q < QQ; ++q) acc[u][q] = 0.f;
        double a64[2] = {0.0, 0.0};

        for (int jb = 0; jb < DHH / 4; jb += 2) {
            float4 kb[2][2];
#pragma unroll
            for (int u = 0; u < 2; ++u) {
                const float4* kp = (const float4*)(kr0 + (size_t)u * 256 * DHH);
                kb[u][0] = kp[jb];
                kb[u][1] = kp[jb + 1];
            }
#pragma unroll
            for (int jj = 0; jj < 2; ++jj) {
#pragma unroll
                for (int q = 0; q < QQ; ++q) {
                    float4 qv = *(const float4*)(qs + q * DHH + (jb + jj) * 4);
#pragma unroll
                    for (int u = 0; u < 2; ++u) {
                        acc[u][q] = fmaf(kb[u][jj].x, qv.x, acc[u][q]);
                        acc[u][q] = fmaf(kb[u][jj].y, qv.y, acc[u][q]);
                        acc[u][q] = fmaf(kb[u][jj].z, qv.z, acc[u][q]);
                        acc[u][q] = fmaf(kb[u][jj].w, qv.w, acc[u][q]);
                    }
                }
            }
#pragma unroll
            for (int jj = 0; jj < 2; ++jj) {
                int j = jb + jj;
#pragma unroll
                for (int u = 0; u < 2; ++u) {
                    a64[u] = fma((double)kb[u][jj].x, q64s[j * 4 + 0], a64[u]);
                    a64[u] = fma((double)kb[u][jj].y, q64s[j * 4 + 1], a64[u]);
                    a64[u] = fma((double)kb[u][jj].z, q64s[j * 4 + 2], a64[u]);
                    a64[u] = fma((double)kb[u][jj].w, q64s[j * 4 + 3], a64[u]);
                }
            }
        }
#pragma unroll
        for (int q = 0; q < QQ; ++q) {
#pragma unroll
            for (int u = 0; u < 2; ++u) {
                int key = kbase + u * 256 + tid;
                float sv = acc[u][q] / 11.313708498984761f;
                if (key > PP + q) sv += -1e9f;
                attn[((size_t)(bh * QQ + q)) * KK + key] = sv;
            }
        }
#pragma unroll
        for (int u = 0; u < 2; ++u)
            sc64[(size_t)bh * KK + kbase + u * 256 + tid] = a64[u] / (double)sqrtf(128.0f);
    } else {
        if (tid >= 16) return;
        const float* krow = kn + ((size_t)bh * QQ + tid) * DHH;
        float acc[QQ];
#pragma unroll
        for (int q = 0; q < QQ; ++q) acc[q] = 0.f;
        for (int j = 0; j < DHH / 4; ++j) {
            float4 kv = ((const float4*)krow)[j];
#pragma unroll
            for (int q = 0; q < QQ; ++q) {
                float4 qv = *(const float4*)(qs + q * DHH + j * 4);
                acc[q] = fmaf(kv.x, qv.x, acc[q]);
                acc[q] = fmaf(kv.y, qv.y, acc[q]);
                acc[q] = fmaf(kv.z, qv.z, acc[q]);
                acc[q] = fmaf(kv.w, qv.w, acc[q]);
            }
        }
        int key = PP + tid;
#pragma unroll
        for (int q = 0; q < QQ; ++q) {
            float sv = acc[q] / 11.313708498984761f;
            if (key > PP + q) sv += -1e9f;
            attn[((size_t)(bh * QQ + q)) * KK + key] = sv;
        }
        double a64 = 0.0;
        const double* kd = k64 + (size_t)(b * QQ + tid) * DD + h * DHH;
        for (int j = 0; j < DHH; ++j) a64 = fma(kd[j], q64s[j], a64);
        sc64[(size_t)bh * KK + key] = a64 / (double)sqrtf(128.0f);
    }
}

// ---------------------------------------------------------------- fused: rowstats f32 (0-511) + rowstats f64 (512-543)
__global__ __launch_bounds__(256) void fused_rowstats_kernel(
    const float* __restrict__ attn, float* __restrict__ rowm, float* __restrict__ rowz,
    const double* __restrict__ sc, double* __restrict__ m64, double* __restrict__ z64)
{
    int bx = blockIdx.x, tid = threadIdx.x;
    __shared__ float sm[256], sz[256];
    __shared__ double dm[256], dz[256];
    if (bx < 512) {
        int row = bx;
        const float* s = attn + (size_t)row * KK;
        float m = -INFINITY, z = 0.f;
        for (int k = tid; k < KK; k += 256) {
            float v = s[k];
            float nm = fmaxf(m, v);
            z = z * expf(m - nm) + expf(v - nm);
            m = nm;
        }
        sm[tid] = m; sz[tid] = z;
        __syncthreads();
        for (int off = 128; off > 0; off >>= 1) {
            if (tid < off) {
                float m1 = sm[tid], z1 = sz[tid];
                float m2 = sm[tid + off], z2 = sz[tid + off];
                float nm = fmaxf(m1, m2);
                sm[tid] = nm;
                sz[tid] = z1 * expf(m1 - nm) + z2 * expf(m2 - nm);
            }
            __syncthreads();
        }
        if (tid == 0) { rowm[row] = sm[0]; rowz[row] = sz[0]; }
    } else {
        int row = bx - 512;
        const double* s = sc + (size_t)row * KK;
        double m = -INFINITY, z = 0.0;
        for (int k = tid; k < KK; k += 256) {
            double v = s[k];
            double nm = fmax(m, v);
            z = z * exp(m - nm) + exp(v - nm);
            m = nm;
        }
        dm[tid] = m; dz[tid] = z;
        __syncthreads();
        for (int off = 128; off > 0; off >>= 1) {
            if (tid < off) {
                double m1 = dm[tid], z1 = dz[tid];
                double m2 = dm[tid + off], z2 = dz[tid + off];
                double nm = fmax(m1, m2);
                dm[tid] = nm;
                dz[tid] = z1 * exp(m1 - nm) + z2 * exp(m2 - nm);
            }
            __syncthreads();
        }
        if (tid == 0) { m64[row] = dm[0]; z64[row] = dz[0]; }
    }
}

// ---------------------------------------------------------------- fused: PV (0-1055) + impkeys (1056-1088)
__global__ __launch_bounds__(256) void fused_pv_impkeys_kernel(
    float* __restrict__ attn, const float* __restrict__ past_v,
    const float* __restrict__ vn, const float* __restrict__ rowm,
    const float* __restrict__ rowz, float* __restrict__ part,
    const double* __restrict__ sc, const double* __restrict__ m64,
    const double* __restrict__ z64, unsigned long long* __restrict__ keys,
    int* __restrict__ rank)
{
    int bx = blockIdx.x, tid = threadIdx.x;
    __shared__ __align__(16) float p[QQ * 256];
    if (bx < 1056) {
        int bh = bx / 33, ch = bx - bh * 33;
        int nk = (ch < 32) ? 256 : 16;
        int kbase = ch * 256;
        if (tid < nk) {
            float sv[QQ];
#pragma unroll
            for (int q = 0; q < QQ; ++q)
                sv[q] = attn[((size_t)(bh * QQ + q)) * KK + kbase + tid];
#pragma unroll
            for (int q = 0; q < QQ; ++q) {
                int row = bh * QQ + q;
                float pv = expf(sv[q] - rowm[row]) / rowz[row];
                attn[((size_t)row) * KK + kbase + tid] = pv;
                p[q * 256 + tid] = pv;
            }
        }
        __syncthreads();

        int dq = tid & 31, q0 = tid >> 5;
        int d4 = dq * 4;
        float4 a0 = make_float4(0, 0, 0, 0), a1 = make_float4(0, 0, 0, 0);
        if (ch < 32) {
            const float* vbase = past_v + ((size_t)bh * PP + kbase) * DHH;
            for (int kk = 0; kk < 256; kk += 8) {
                float4 vb[8];
#pragma unroll
                for (int u = 0; u < 8; ++u)
                    vb[u] = *(const float4*)(vbase + (size_t)(kk + u) * DHH + d4);
#pragma unroll
                for (int u = 0; u < 8; ++u) {
                    float p0 = p[q0 * 256 + kk + u];
                    float p1 = p[(q0 + 8) * 256 + kk + u];
                    a0.x = fmaf(vb[u].x, p0, a0.x); a0.y = fmaf(vb[u].y, p0, a0.y);
                    a0.z = fmaf(vb[u].z, p0, a0.z); a0.w = fmaf(vb[u].w, p0, a0.w);
                    a1.x = fmaf(vb[u].x, p1, a1.x); a1.y = fmaf(vb[u].y, p1, a1.y);
                    a1.z = fmaf(vb[u].z, p1, a1.z); a1.w = fmaf(vb[u].w, p1, a1.w);
                }
            }
        } else {
            const float* vbase = vn + (size_t)bh * QQ * DHH;
            for (int kk = 0; kk < 16; ++kk) {
                float4 v4 = *(const float4*)(vbase + (size_t)kk * DHH + d4);
                float p0 = p[q0 * 256 + kk];
                float p1 = p[(q0 + 8) * 256 + kk];
                a0.x = fmaf(v4.x, p0, a0.x); a0.y = fmaf(v4.y, p0, a0.y);
                a0.z = fmaf(v4.z, p0, a0.z); a0.w = fmaf(v4.w, p0, a0.w);
                a1.x = fmaf(v4.x, p1, a1.x); a1.y = fmaf(v4.y, p1, a1.y);
                a1.z = fmaf(v4.z, p1, a1.z); a1.w = fmaf(v4.w, p1, a1.w);
            }
        }
        size_t pb = ((size_t)ch * BH + bh) * (QQ * DHH);
        *(float4*)(part + pb + q0 * DHH + d4) = a0;
        *(float4*)(part + pb + (q0 + 8) * DHH + d4) = a1;
    } else {
        int k = (bx - 1056) * 256 + tid;
        if (k >= KK) return;
        rank[k] = 0;
        double t = 0.0;
        for (int bh = 0; bh < BH; ++bh)
            t += exp(sc[(size_t)bh * KK + k] - m64[bh]) / z64[bh];
        double imp = t / 32.0;
        if (k == KK - 1) imp = INFINITY;
        unsigned long long bits = (unsigned long long)__double_as_longlong(imp);
        keys[k] = (bits & ~0x3FFFull) | (unsigned long long)k;
    }
}

// ---------------------------------------------------------------- fused: PV reduce (0-255) + rankpart (256-519)
__global__ __launch_bounds__(256) void fused_pvred_rankpart_kernel(
    const float* __restrict__ part, float* __restrict__ oattn,
    const unsigned long long* __restrict__ keys, int* __restrict__ rank)
{
    int bx = blockIdx.x, tid = threadIdx.x;
    __shared__ unsigned long long chnk[1026];
    if (bx < 256) {
        int e = bx * 256 + tid;
        float sa = 0.f, sb = 0.f;
#pragma unroll 8
        for (int ch = 0; ch < 16; ++ch) sa += part[(size_t)ch * 65536 + e];
#pragma unroll 8
        for (int ch = 16; ch < 33; ++ch) sb += part[(size_t)ch * 65536 + e];
        float s = sa + sb;
        int bh = e >> 11, rem = e & 2047, q = rem >> 7, d = rem & 127;
        int b = bh >> 4, h = bh & 15;
        oattn[((size_t)(b * QQ + q)) * DD + h * DHH + d] = s;
    } else {
        int idx = bx - 256;           // 0..263
        int xb = idx % 33, yb = idx / 33;
        int gid = xb * 256 + tid;
        int base = yb * 1026;
        for (int i = tid; i < 1026; i += 256) chnk[i] = keys[base + i];
        __syncthreads();
        if (gid >= KK) return;
        unsigned long long mykey = keys[gid];
        int cnt = 0;
#pragma unroll 6
        for (int i = 0; i < 1026; ++i) cnt += (chnk[i] < mykey) ? 1 : 0;
        atomicAdd(&rank[gid], cnt);
    }
}

// ---------------------------------------------------------------- fused: Wo GEMM (0-255) + rankwrite (256-288)
__global__ __launch_bounds__(256) void fused_wogemm_rankwrite_kernel(
    const float* __restrict__ A, const float* __restrict__ wo,
    float* __restrict__ part,
    const unsigned long long* __restrict__ keys, const int* __restrict__ rank,
    float* __restrict__ outp)
{
    int bx = blockIdx.x, tid = threadIdx.x;
    __shared__ __align__(16) float xs[32 * 32];
    if (bx < 256) {
        int cc = bx & 3, kc = bx >> 2;
        int col0 = cc * 512 + tid;
        int d0 = kc * 32;
        for (int i = tid; i < 32 * 32; i += 256) {
            int r = i >> 5, d = i & 31;
            xs[i] = A[(size_t)r * DD + d0 + d];
        }
        __syncthreads();
        float acc0[32], acc1[32];
#pragma unroll
        for (int r = 0; r < 32; ++r) { acc0[r] = 0.f; acc1[r] = 0.f; }
        const float* wp = wo + (size_t)d0 * DD + col0;
        for (int d = 0; d < 32; d += 8) {
            float wb0[8], wb1[8];
#pragma unroll
            for (int u = 0; u < 8; ++u) {
                wb0[u] = wp[(size_t)(d + u) * DD];
                wb1[u] = wp[(size_t)(d + u) * DD + 256];
            }
#pragma unroll
            for (int r = 0; r < 32; ++r) {
                const float4 x0 = *(const float4*)(xs + r * 32 + d);
                const float4 x1 = *(const float4*)(xs + r * 32 + d + 4);
                float a = acc0[r], b = acc1[r];
                a = fmaf(x0.x, wb0[0], a);  b = fmaf(x0.x, wb1[0], b);
                a = fmaf(x0.y, wb0[1], a);  b = fmaf(x0.y, wb1[1], b);
                a = fmaf(x0.z, wb0[2], a);  b = fmaf(x0.z, wb1[2], b);
                a = fmaf(x0.w, wb0[3], a);  b = fmaf(x0.w, wb1[3], b);
                a = fmaf(x1.x, wb0[4], a);  b = fmaf(x1.x, wb1[4], b);
                a = fmaf(x1.y, wb0[5], a);  b = fmaf(x1.y, wb1[5], b);
                a = fmaf(x1.z, wb0[6], a);  b = fmaf(x1.z, wb1[6], b);
                a = fmaf(x1.w, wb0[7], a);  b = fmaf(x1.w, wb1[7], b);
                acc0[r] = a; acc1[r] = b;
            }
        }
#pragma unroll
        for (int r = 0; r < 32; ++r) {
            part[((size_t)(kc * 32 + r)) * DD + col0] = acc0[r];
            part[((size_t)(kc * 32 + r)) * DD + col0 + 256] = acc1[r];
        }
    } else {
        int gid = (bx - 256) * 256 + tid;
        if (gid >= KK) return;
        int r = rank[gid];
        if (r < NPRUNE)
            outp[r] = (float)(unsigned)(keys[gid] & 0x3FFFu);
    }
}

// ---------------------------------------------------------------- Wo reduce + residual (dual 32+32)
__global__ __launch_bounds__(256) void reduce_wo_kernel(
    const float* __restrict__ part, const float* __restrict__ resid,
    float* __restrict__ hbuf)
{
    int e = blockIdx.x * 256 + threadIdx.x;
    float sa = 0.f, sb = 0.f;
#pragma unroll 8
    for (int kc = 0; kc < 32; ++kc) {
        sa += part[(size_t)kc * 65536 + e];
        sb += part[(size_t)(kc + 32) * 65536 + e];
    }
    hbuf[e] = resid[e] + (sa + sb);
}

// ---------------------------------------------------------------- fused gate+up reduce + silu (dual streams each)
__global__ __launch_bounds__(256) void reduce_gateup_silu_kernel(
    const float* __restrict__ part, float* __restrict__ act)
{
    int e = blockIdx.x * 256 + threadIdx.x;
    float ga = 0.f, gb = 0.f, ua = 0.f, ub = 0.f;
#pragma unroll 8
    for (int kc = 0; kc < 16; ++kc) {
        ga += part[(size_t)kc * 180224 + e];
        gb += part[(size_t)(kc + 16) * 180224 + e];
        ua += part[(size_t)(kc + 32) * 180224 + e];
        ub += part[(size_t)(kc + 48) * 180224 + e];
    }
    float g = ga + gb, u = ua + ub;
    float sg = g / (1.f + expf(-g));
    act[e] = sg * u;
}

// ---------------------------------------------------------------- down reduce + residual (dual 88+88)
__global__ __launch_bounds__(256) void reduce_down_kernel(
    const float* __restrict__ part, const float* __restrict__ hbuf,
    float* __restrict__ out)
{
    int e = blockIdx.x * 256 + threadIdx.x;
    float sa = 0.f, sb = 0.f;
#pragma unroll 8
    for (int kc = 0; kc < 88; ++kc) {
        sa += part[(size_t)kc * 65536 + e];
        sb += part[(size_t)(kc + 88) * 65536 + e];
    }
    out[e] = hbuf[e] + (sa + sb);
}

// ================================================================ launch
extern "C" void kernel_launch(void* const* d_in, const int* in_sizes, int n_in,
                              void* d_out, int out_size, void* d_ws, size_t ws_size,
                              hipStream_t stream)
{
    const float* hidden = (const float*)d_in[0];
    const float* past_k = (const float*)d_in[1];
    const float* past_v = (const float*)d_in[2];
    const float* wq     = (const float*)d_in[3];
    const float* wk     = (const float*)d_in[4];
    const float* wv     = (const float*)d_in[5];
    const float* wo     = (const float*)d_in[6];
    const float* wgate  = (const float*)d_in[7];
    const float* wup    = (const float*)d_in[8];
    const float* wdown  = (const float*)d_in[9];
    const float* n1w    = (const float*)d_in[10];
    const float* n2w    = (const float*)d_in[11];

    float* out_hidden = (float*)d_out;
    float* attn = out_hidden + (size_t)RR * DD;
    float* out_prune = attn + (size_t)BH * QQ * KK;
    float* ws = (float*)d_ws;
    double* p64part = (double*)(ws + OFF_P64P);
    double* f64 = (double*)(ws + OFF_F64);
    double* x64 = f64 + D_X64;
    double* k64 = f64 + D_K64;
    double* q64 = f64 + D_Q64;
    double* m64 = f64 + D_M64;
    double* z64 = f64 + D_Z64;
    double* sc64 = f64 + D_SC;
    unsigned long long* keys = (unsigned long long*)(f64 + D_KEYS);
    int* rank = (int*)(ws + OFF_RANK);

    // 1. rmsnorm1 + rms32mix (fused)
    fused_rms_kernel<<<dim3(64), dim3(256), 0, stream>>>(hidden, n1w, ws + OFF_X, x64);

    // 2. QKV GEMM (768) + proj64_part (256) fused
    fused_qkv_p64_kernel<<<dim3(1024), dim3(256), 0, stream>>>(
        ws + OFF_X, wq, wk, wv, ws + OFF_UNION, x64, p64part);

    // 3. QKV reduce+RoPE (256) + proj64 reduce+RoPE (272) fused
    fused_reduce_kernel<<<dim3(528), dim3(256), 0, stream>>>(
        ws + OFF_UNION, ws + OFF_QR, ws + OFF_KN, ws + OFF_VN, p64part, k64, q64);

    // 4. scores (f32 + fused f64)
    scores_kernel<<<dim3(BH, 17), dim3(256), 0, stream>>>(
        ws + OFF_QR, past_k, ws + OFF_KN, attn, q64, k64, sc64);

    // 5. rowstats f32 (512) + f64 (32) fused
    fused_rowstats_kernel<<<dim3(544), dim3(256), 0, stream>>>(
        attn, ws + OFF_ROWM, ws + OFF_ROWZ, sc64, m64, z64);

    // 6. PV (1056) + impkeys (33) fused
    fused_pv_impkeys_kernel<<<dim3(1089), dim3(256), 0, stream>>>(
        attn, past_v, ws + OFF_VN, ws + OFF_ROWM, ws + OFF_ROWZ, ws + OFF_UNION,
        sc64, m64, z64, keys, rank);

    // 7. PV reduce (256) + rankpart (264) fused
    fused_pvred_rankpart_kernel<<<dim3(520), dim3(256), 0, stream>>>(
        ws + OFF_UNION, ws + OFF_OATTN, keys, rank);

    // 8. Wo GEMM (256) + rankwrite (33) fused
    fused_wogemm_rankwrite_kernel<<<dim3(289), dim3(256), 0, stream>>>(
        ws + OFF_OATTN, wo, ws + OFF_UNION, keys, rank, out_prune);

    // 9. + residual
    reduce_wo_kernel<<<dim3(256), dim3(256), 0, stream>>>(ws + OFF_UNION, hidden, ws + OFF_H);

    // 10. rmsnorm2
    rmsnorm_kernel<<<dim3(RR), dim3(256), 0, stream>>>(ws + OFF_H, n2w, ws + OFF_Y);

    // 11. gate+up GEMM — C=2, 32 k-splits, 704 blocks; fused reduce+silu
    gemm32c2<64><<<dim3(11, 32, 2), dim3(256), 0, stream>>>(
        ws + OFF_Y, wgate, wup, wup, ws + OFF_UNION, DD, FF, (size_t)32 * 180224);
    reduce_gateup_silu_kernel<<<dim3(704), dim3(256), 0, stream>>>(
        ws + OFF_UNION, ws + OFF_ACT);

    // 12. down GEMM — C=2, 176 k-splits, 704 blocks
    gemm32c2<32><<<dim3(4, 176, 1), dim3(256), 0, stream>>>(
        ws + OFF_ACT, wdown, wdown, wdown, ws + OFF_UNION, FF, DD, 0);
    reduce_down_kernel<<<dim3(256), dim3(256), 0, stream>>>(
        ws + OFF_UNION, ws + OFF_H, out_hidden);
}